// Round 19
// baseline (288.894 us; speedup 1.0000x reference)
//
#include <hip/hip_runtime.h>
#include <hip/hip_bf16.h>
#include <math.h>

// B=4, NQ=300, NC=16, C=256, NH=8, NP=4, DFF=2048, H=W=128, Lq=4800, hd=32

typedef unsigned short u16;
typedef unsigned int u32;
typedef __attribute__((ext_vector_type(4))) float f32x4;
typedef __attribute__((ext_vector_type(8))) short s16x8;

__device__ __forceinline__ float b2f(u16 u) {
    union { u32 u; float f; } v; v.u = ((u32)u) << 16; return v.f;
}
__device__ __forceinline__ u16 f2b(float f) {
    union { float f; u32 u; } v; v.f = f;
    u32 r = v.u + 0x7fffu + ((v.u >> 16) & 1u);
    return (u16)(r >> 16);
}
__device__ __forceinline__ u32 pkbf(float a, float b) {
    u32 r;
    asm("v_cvt_pk_bf16_f32 %0, %1, %2" : "=v"(r) : "v"(a), "v"(b));
    return r;
}

#define GLOAD_LDS16(g, l) \
    __builtin_amdgcn_global_load_lds((const __attribute__((address_space(1))) void*)(g), \
                                     (__attribute__((address_space(3))) void*)(l), 16, 0, 0)

// ---------------------------------------------------------------------------
// Fused fp32 -> bf16 conversion over up to 8 segments (all sizes % 8 == 0)
// ---------------------------------------------------------------------------
struct CvtSeg { const float* src; u16* dst; int nv; };  // nv = elems/8
struct Cvt8 { CvtSeg s[8]; };

__global__ __launch_bounds__(256) void cvt_multi(Cvt8 a, int totalv) {
    int v = blockIdx.x * 256 + threadIdx.x;
    if (v >= totalv) return;
    int si = 0;
    while (si < 7 && v >= a.s[si].nv) { v -= a.s[si].nv; ++si; }
    const float* src = a.s[si].src + (size_t)v * 8;
    u16* dst = a.s[si].dst + (size_t)v * 8;
    float4 x = *(const float4*)src;
    float4 y = *(const float4*)(src + 4);
    u16 u[8] = { f2b(x.x), f2b(x.y), f2b(x.z), f2b(x.w),
                 f2b(y.x), f2b(y.y), f2b(y.z), f2b(y.w) };
    *(uint4*)dst = *(const uint4*)u;
}

// pack off_w(64)+aw_w(32)+zeros(32) -> [128][256] bf16, bias -> [128] f32;
// also zeros a 256-float scratch bias (for split-K partial GEMMs).
__global__ __launch_bounds__(256) void pack_offaw(
    const float* __restrict__ off_w, const float* __restrict__ off_b,
    const float* __restrict__ aw_w, const float* __restrict__ aw_b,
    u16* __restrict__ wout, float* __restrict__ bout, float* __restrict__ zbuf)
{
    int r = blockIdx.x, c = threadIdx.x;
    float v = 0.f;
    if (r < 64) v = off_w[r * 256 + c];
    else if (r < 96) v = aw_w[(r - 64) * 256 + c];
    wout[r * 256 + c] = f2b(v);
    if (c == 0) bout[r] = (r < 64) ? off_b[r] : (r < 96 ? aw_b[r - 64] : 0.f);
    if (r == 0) zbuf[c] = 0.f;
}

// ---------------------------------------------------------------------------
// MFMA bf16 GEMM: C[M,N] = A[M,K] @ W[N,K]^T + bias. Tile TM x 128, BK=64/128.
// LDK = row stride. Split-K via gridDim.z (co-resident slabs). Chunk-XOR
// involution, bijective per-z-slice XCD swizzle, LDS bf16 epilogue.
// ---------------------------------------------------------------------------
template<int RELU, int OUTBF16, int TM, int BK>
__global__ __launch_bounds__(256) void gemm_mfma(
    const u16* __restrict__ A, const u16* __restrict__ W,
    const float* __restrict__ bias, void* __restrict__ Cout,
    int M, int N, int K, int LDK,
    const float* __restrict__ bias2, void* __restrict__ Cout2)
{
    constexpr int MI = TM / 32;            // row-frags per wave (4 or 2)
    constexpr int CR = BK / 8;             // 16B-chunks per row
    constexpr int CHA = TM * BK / 2048;    // A chunks per thread per step
    constexpr int CHB = 128 * BK / 2048;   // B chunks per thread per step
    __shared__ u16 smem[(TM + 128) * BK];
    u16* Asm = smem;
    u16* Bsm = smem + TM * BK;
    const int tid = threadIdx.x;
    const int wave = tid >> 6, lane = tid & 63;
    // --- split-K slab select (z-slice)
    const int ks = blockIdx.z;
    if (ks) { bias = bias2; Cout = Cout2; }
    A += (size_t)ks * K;
    W += (size_t)ks * K;
    // --- bijective XCD swizzle (m204), per z-slice
    const int gx = gridDim.x;
    const int nwg = gx * gridDim.y;
    const int lid = blockIdx.y * gx + blockIdx.x;
    const int q8 = nwg >> 3, r8 = nwg & 7;
    const int xcd = lid & 7, sub = lid >> 3;
    const int logical = (xcd < r8 ? xcd * (q8 + 1) : r8 * (q8 + 1) + (xcd - r8) * q8) + sub;
    const int bm = (logical / gx) * TM, bn = (logical % gx) * 128;
    const int wr = (wave >> 1) * (TM / 2), wc = (wave & 1) * 64;
    const int fr = lane & 15;
    const int g = lane >> 4;
    const int sw = fr & (CR - 1);
    f32x4 acc[MI][4] = {};

    for (int k0 = 0; k0 < K; k0 += BK) {
        __syncthreads();
#pragma unroll
        for (int c = 0; c < CHA; ++c) {
            int L = c * 256 + tid;              // 16B-chunk id in A tile
            int r = L / CR, p = L % CR;         // row, physical chunk in row
            int cc = p ^ (r & (CR - 1));        // logical k-chunk (involution)
            int ra = bm + r; if (ra >= M) ra = M - 1;
            GLOAD_LDS16(A + (size_t)ra * LDK + k0 + cc * 8, Asm + (c * 256 + wave * 64) * 8);
        }
#pragma unroll
        for (int c = 0; c < CHB; ++c) {
            int L = c * 256 + tid;
            int r = L / CR, p = L % CR;
            int cc = p ^ (r & (CR - 1));
            int rb = bn + r;
            GLOAD_LDS16(W + (size_t)rb * LDK + k0 + cc * 8, Bsm + (c * 256 + wave * 64) * 8);
        }
        __syncthreads();
#pragma unroll
        for (int kk = 0; kk < BK / 32; ++kk) {
            const int pc = (kk * 4 + g) ^ sw;   // physical chunk for this frag
            s16x8 af[MI], bf[4];
#pragma unroll
            for (int i = 0; i < MI; ++i)
                af[i] = *(const s16x8*)(Asm + (wr + i * 16 + fr) * BK + pc * 8);
#pragma unroll
            for (int i = 0; i < 4; ++i)
                bf[i] = *(const s16x8*)(Bsm + (wc + i * 16 + fr) * BK + pc * 8);
#pragma unroll
            for (int mi = 0; mi < MI; ++mi)
#pragma unroll
                for (int ni = 0; ni < 4; ++ni)
                    acc[mi][ni] = __builtin_amdgcn_mfma_f32_16x16x32_bf16(
                        af[mi], bf[ni], acc[mi][ni], 0, 0, 0);
        }
    }
    const int cc = lane & 15, cr4 = (lane >> 4) * 4;
    if (OUTBF16) {
        // repack in 32-row passes: smem[32][136] (272B stride)
#pragma unroll
        for (int p = 0; p < TM / 32; ++p) {
            const int base = p * 32;
            __syncthreads();
#pragma unroll
            for (int mi = 0; mi < MI; ++mi) {
                int rowoff = wr + mi * 16;
                if (rowoff < base || rowoff >= base + 32) continue;
#pragma unroll
                for (int ni = 0; ni < 4; ++ni) {
                    int col = wc + ni * 16 + cc;
                    float bv = bias[bn + col];
#pragma unroll
                    for (int j = 0; j < 4; ++j) {
                        float v = acc[mi][ni][j] + bv;
                        if (RELU) v = fmaxf(v, 0.f);
                        smem[(rowoff - base + cr4 + j) * 136 + col] = f2b(v);
                    }
                }
            }
            __syncthreads();
            for (int t = tid; t < 512; t += 256) {
                int row = t >> 4, ck = t & 15;
                int grow = bm + base + row;
                if (grow < M)
                    *(uint4*)((u16*)Cout + (size_t)grow * N + bn + ck * 8) =
                        *(const uint4*)&smem[row * 136 + ck * 8];
            }
        }
    } else {
#pragma unroll
        for (int mi = 0; mi < MI; ++mi) {
#pragma unroll
            for (int ni = 0; ni < 4; ++ni) {
                int col = bn + wc + ni * 16 + cc;
                float bv = bias[col];
#pragma unroll
                for (int j = 0; j < 4; ++j) {
                    int row = bm + wr + mi * 16 + cr4 + j;
                    if (row >= M) continue;
                    float v = acc[mi][ni][j] + bv;
                    if (RELU) v = fmaxf(v, 0.f);
                    ((float*)Cout)[(size_t)row * N + col] = v;
                }
            }
        }
    }
}

// ---------------------------------------------------------------------------
// MFMA flash attention, swapped-operand, online softmax with 64-key chunks.
// S=1 for the sc path: one block per (bi,h) — eliminates the duplicate K/V
// staging that S=2 paid (concurrent segs both L2-missed the same 77 KB).
// Vt swizzle with T4(d>>3): staging u32 writes 2-way; b128 reads 8/quad.
// ---------------------------------------------------------------------------
#define T4(s) ((((s) << 1) ^ (s)) & 7)   // {0,3,6,5} for s=0..3
#define VIDX(d, k) (((((k) >> 3) ^ ((d) & 7) ^ T4((d) >> 3)) << 3) + ((k) & 7))

__global__ __launch_bounds__(256) void attn_mfma(
    const u16* __restrict__ qkv, u16* __restrict__ O, int S, int NBH)
{
    const int bh = blockIdx.x % NBH, seg = blockIdx.x / NBH;
    const int bi = bh >> 3, h = bh & 7;
    __shared__ u16 Ks[320][40];    // K raw, row-major (80B stride: conflict-free)
    __shared__ u16 Vt[32][320];    // V transposed, XOR-swizzled chunks
    const int tid = threadIdx.x;

    for (int idx = tid; idx < 1200; idx += 256) {
        int k = idx >> 2, sub = idx & 3;
        const u16* kp = qkv + ((size_t)(bi * 300 + k)) * 768 + 256 + h * 32 + sub * 8;
        *(uint4*)&Ks[k][sub * 8] = *(const uint4*)kp;
    }
    for (int idx = tid; idx < 600; idx += 256) {
        int kp2 = idx >> 2, sub = idx & 3;
        int k0 = kp2 * 2;
        const u16* vp = qkv + ((size_t)(bi * 300 + k0)) * 768 + 512 + h * 32 + sub * 8;
        uint4 v0 = *(const uint4*)vp;
        uint4 v1 = *(const uint4*)(vp + 768);
        u16 a0[8], a1[8];
        *(uint4*)a0 = v0; *(uint4*)a1 = v1;
#pragma unroll
        for (int j = 0; j < 8; ++j) {
            int d = sub * 8 + j;
            *(u32*)&Vt[d][VIDX(d, k0)] = (u32)a0[j] | ((u32)a1[j] << 16);
        }
    }
    for (int idx = tid; idx < 320; idx += 256) {
        int d = idx & 31, k0 = 300 + (idx >> 5) * 2;
        *(u32*)&Vt[d][VIDX(d, k0)] = 0;
    }
    __syncthreads();

    const int lane = tid & 63, wave = tid >> 6;
    const int c = lane & 15, g = lane >> 4;
    const int fk = g * 8;
    const f32x4 zero = { 0.f, 0.f, 0.f, 0.f };
    const float SCL2 = 0.25505416f;           // (1/sqrt(32)) * log2(e)
    const int sA = c + ((g & 1) << 5);
    const int sB = sA + 16;
    const bool hi = g >= 2;

    for (int qt = seg * 4 + wave; qt < 19; qt += 4 * S) {
        int qrow = qt * 16 + c; if (qrow > 299) qrow = 299;
        s16x8 afq = *(const s16x8*)(qkv + ((size_t)(bi * 300 + qrow)) * 768 + h * 32 + fk);
        f32x4 acc0 = zero, acc1 = zero;
        float m = -1e30f, l = 0.f;

        for (int kc = 0; kc < 5; ++kc) {
            const int kb = kc * 64;
            s16x8 ak0 = *(const s16x8*)&Ks[kb + c][fk];
            s16x8 ak1 = *(const s16x8*)&Ks[kb + 16 + c][fk];
            s16x8 ak2 = *(const s16x8*)&Ks[kb + 32 + c][fk];
            s16x8 ak3 = *(const s16x8*)&Ks[kb + 48 + c][fk];
            __builtin_amdgcn_s_setprio(1);
            f32x4 s0 = __builtin_amdgcn_mfma_f32_16x16x32_bf16(ak0, afq, zero, 0, 0, 0);
            f32x4 s1 = __builtin_amdgcn_mfma_f32_16x16x32_bf16(ak1, afq, zero, 0, 0, 0);
            f32x4 s2 = __builtin_amdgcn_mfma_f32_16x16x32_bf16(ak2, afq, zero, 0, 0, 0);
            f32x4 s3 = __builtin_amdgcn_mfma_f32_16x16x32_bf16(ak3, afq, zero, 0, 0, 0);
            __builtin_amdgcn_s_setprio(0);
            if (kb == 256) {   // keys >= 300 invalid (overwrite kills NaN)
#pragma unroll
                for (int j = 0; j < 4; ++j) {
                    if (g == 3) s2[j] = -1e30f;
                    s3[j] = -1e30f;
                }
            }
            float cm = fmaxf(fmaxf(fmaxf(s0[0], s0[1]), fmaxf(s0[2], s0[3])),
                             fmaxf(fmaxf(s1[0], s1[1]), fmaxf(s1[2], s1[3])));
            float cm2 = fmaxf(fmaxf(fmaxf(s2[0], s2[1]), fmaxf(s2[2], s2[3])),
                              fmaxf(fmaxf(s3[0], s3[1]), fmaxf(s3[2], s3[3])));
            cm = fmaxf(cm, cm2);
            cm = fmaxf(cm, __shfl_xor(cm, 16));
            cm = fmaxf(cm, __shfl_xor(cm, 32));
            float mn = fmaxf(m, cm);
            float corr = exp2f((m - mn) * SCL2);
            m = mn;
            float p0[4], p1[4], p2[4], p3[4];
#pragma unroll
            for (int j = 0; j < 4; ++j) {
                p0[j] = exp2f((s0[j] - m) * SCL2);
                p1[j] = exp2f((s1[j] - m) * SCL2);
                p2[j] = exp2f((s2[j] - m) * SCL2);
                p3[j] = exp2f((s3[j] - m) * SCL2);
            }
            float cs = ((p0[0] + p0[1]) + (p0[2] + p0[3]))
                     + ((p1[0] + p1[1]) + (p1[2] + p1[3]))
                     + ((p2[0] + p2[1]) + (p2[2] + p2[3]))
                     + ((p3[0] + p3[1]) + (p3[2] + p3[3]));
            cs += __shfl_xor(cs, 16);
            cs += __shfl_xor(cs, 32);
            l = l * corr + cs;
            u32 w0 = pkbf(p0[0], p0[1]), w1 = pkbf(p0[2], p0[3]);
            u32 w2 = pkbf(p1[0], p1[1]), w3 = pkbf(p1[2], p1[3]);
            u32 w4 = pkbf(p2[0], p2[1]), w5 = pkbf(p2[2], p2[3]);
            u32 w6 = pkbf(p3[0], p3[1]), w7 = pkbf(p3[2], p3[3]);
            int x0 = __shfl((int)w0, sA), x1 = __shfl((int)w1, sA);
            int x2 = __shfl((int)w2, sA), x3 = __shfl((int)w3, sA);
            int y0 = __shfl((int)w0, sB), y1 = __shfl((int)w1, sB);
            int y2 = __shfl((int)w2, sB), y3 = __shfl((int)w3, sB);
            union { u32 w[4]; s16x8 v; } afpA;
            afpA.w[0] = hi ? (u32)x2 : (u32)x0;
            afpA.w[1] = hi ? (u32)x3 : (u32)x1;
            afpA.w[2] = hi ? (u32)y2 : (u32)y0;
            afpA.w[3] = hi ? (u32)y3 : (u32)y1;
            int x4 = __shfl((int)w4, sA), x5 = __shfl((int)w5, sA);
            int x6 = __shfl((int)w6, sA), x7 = __shfl((int)w7, sA);
            int y4 = __shfl((int)w4, sB), y5 = __shfl((int)w5, sB);
            int y6 = __shfl((int)w6, sB), y7 = __shfl((int)w7, sB);
            union { u32 w[4]; s16x8 v; } afpB;
            afpB.w[0] = hi ? (u32)x6 : (u32)x4;
            afpB.w[1] = hi ? (u32)x7 : (u32)x5;
            afpB.w[2] = hi ? (u32)y6 : (u32)y4;
            afpB.w[3] = hi ? (u32)y7 : (u32)y5;
            float c0 = __shfl(corr, g * 4 + 0), c1 = __shfl(corr, g * 4 + 1);
            float c2 = __shfl(corr, g * 4 + 2), c3 = __shfl(corr, g * 4 + 3);
            acc0[0] *= c0; acc0[1] *= c1; acc0[2] *= c2; acc0[3] *= c3;
            acc1[0] *= c0; acc1[1] *= c1; acc1[2] *= c2; acc1[3] *= c3;
            s16x8 bv0 = *(const s16x8*)&Vt[c][VIDX(c, kb + fk)];
            s16x8 bv1 = *(const s16x8*)&Vt[16 + c][VIDX(16 + c, kb + fk)];
            s16x8 bv2 = *(const s16x8*)&Vt[c][VIDX(c, kb + 32 + fk)];
            s16x8 bv3 = *(const s16x8*)&Vt[16 + c][VIDX(16 + c, kb + 32 + fk)];
            __builtin_amdgcn_s_setprio(1);
            acc0 = __builtin_amdgcn_mfma_f32_16x16x32_bf16(afpA.v, bv0, acc0, 0, 0, 0);
            acc1 = __builtin_amdgcn_mfma_f32_16x16x32_bf16(afpA.v, bv1, acc1, 0, 0, 0);
            acc0 = __builtin_amdgcn_mfma_f32_16x16x32_bf16(afpB.v, bv2, acc0, 0, 0, 0);
            acc1 = __builtin_amdgcn_mfma_f32_16x16x32_bf16(afpB.v, bv3, acc1, 0, 0, 0);
            __builtin_amdgcn_s_setprio(0);
        }
        float l0 = __shfl(l, g * 4 + 0), l1 = __shfl(l, g * 4 + 1);
        float l2 = __shfl(l, g * 4 + 2), l3 = __shfl(l, g * 4 + 3);
        float lj[4] = { l0, l1, l2, l3 };
#pragma unroll
        for (int j = 0; j < 4; ++j) {
            int q = qt * 16 + g * 4 + j;
            if (q < 300) {
                float r = 1.f / lj[j];
                u16* op = O + ((size_t)(bi * 300 + q)) * 256 + h * 32;
                op[c]      = f2b(acc0[j] * r);
                op[16 + c] = f2b(acc1[j] * r);
            }
        }
    }
}

// sc_x[(b*16+nc)*300+nq][c] = sub_contour_query[b][nq][nc][c]  (bf16 out)
__global__ __launch_bounds__(256) void sc_transpose(
    const float* __restrict__ scq, u16* __restrict__ out)
{
    int row = blockIdx.x * 4 + (threadIdx.x >> 6);
    int c4 = (threadIdx.x & 63) * 4;
    int b = row / 4800;
    int rem = row % 4800;
    int nc = rem / 300, nq = rem % 300;
    float4 v = *(const float4*)(scq + ((size_t)((b * 300 + nq) * 16 + nc)) * 256 + c4);
    u16 u[4] = { f2b(v.x), f2b(v.y), f2b(v.z), f2b(v.w) };
    *(uint2*)(out + (size_t)row * 256 + c4) = *(const uint2*)u;
}

// tgt = LN( scq + 2*(sc_o + inst_o) ); 4 rows/block, row == wave, no LDS
__global__ __launch_bounds__(256) void ln1_combine(
    const float* __restrict__ scq, const float* __restrict__ sco,
    const float* __restrict__ insto, const float* __restrict__ g,
    const float* __restrict__ bta, float* __restrict__ tgt,
    u16* __restrict__ tgtb)
{
    int row = blockIdx.x * 4 + (threadIdx.x >> 6);
    int c4 = (threadIdx.x & 63) * 4;
    int b = row / 4800;
    int rem = row % 4800;
    int nq = rem >> 4, nc = rem & 15;
    float4 a = *(const float4*)(scq + (size_t)row * 256 + c4);
    float4 s = *(const float4*)(sco + ((size_t)((b * 16 + nc) * 300 + nq)) * 256 + c4);
    float4 i = *(const float4*)(insto + ((size_t)(b * 300 + nq)) * 256 + c4);
    float4 v = { a.x + 2.f * (s.x + i.x), a.y + 2.f * (s.y + i.y),
                 a.z + 2.f * (s.z + i.z), a.w + 2.f * (s.w + i.w) };
    float sm = v.x + v.y + v.z + v.w;
    float s2 = v.x * v.x + v.y * v.y + v.z * v.z + v.w * v.w;
#pragma unroll
    for (int o = 32; o; o >>= 1) { sm += __shfl_xor(sm, o); s2 += __shfl_xor(s2, o); }
    float mean = sm * (1.f / 256.f);
    float rstd = 1.f / sqrtf(s2 * (1.f / 256.f) - mean * mean + 1e-5f);
    float4 gv = *(const float4*)(g + c4);
    float4 bv = *(const float4*)(bta + c4);
    float4 r = { (v.x - mean) * rstd * gv.x + bv.x, (v.y - mean) * rstd * gv.y + bv.y,
                 (v.z - mean) * rstd * gv.z + bv.z, (v.w - mean) * rstd * gv.w + bv.w };
    *(float4*)(tgt + (size_t)row * 256 + c4) = r;
    u16 u[4] = { f2b(r.x), f2b(r.y), f2b(r.z), f2b(r.w) };
    *(uint2*)(tgtb + (size_t)row * 256 + c4) = *(const uint2*)u;
}

// dst = LN(x + y); optional bf16 copy; 4 rows/block, row == wave, no LDS
__global__ __launch_bounds__(256) void ln_add(
    const float* __restrict__ x, const float* __restrict__ y,
    const float* __restrict__ g, const float* __restrict__ bta,
    float* __restrict__ dst, u16* __restrict__ bdst)
{
    int row = blockIdx.x * 4 + (threadIdx.x >> 6);
    int c4 = (threadIdx.x & 63) * 4;
    float4 a = *(const float4*)(x + (size_t)row * 256 + c4);
    float4 b = *(const float4*)(y + (size_t)row * 256 + c4);
    float4 v = { a.x + b.x, a.y + b.y, a.z + b.z, a.w + b.w };
    float sm = v.x + v.y + v.z + v.w;
    float s2 = v.x * v.x + v.y * v.y + v.z * v.z + v.w * v.w;
#pragma unroll
    for (int o = 32; o; o >>= 1) { sm += __shfl_xor(sm, o); s2 += __shfl_xor(s2, o); }
    float mean = sm * (1.f / 256.f);
    float rstd = 1.f / sqrtf(s2 * (1.f / 256.f) - mean * mean + 1e-5f);
    float4 gv = *(const float4*)(g + c4);
    float4 bv = *(const float4*)(bta + c4);
    float4 r = { (v.x - mean) * rstd * gv.x + bv.x, (v.y - mean) * rstd * gv.y + bv.y,
                 (v.z - mean) * rstd * gv.z + bv.z, (v.w - mean) * rstd * gv.w + bv.w };
    *(float4*)(dst + (size_t)row * 256 + c4) = r;
    if (bdst) {
        u16 u[4] = { f2b(r.x), f2b(r.y), f2b(r.z), f2b(r.w) };
        *(uint2*)(bdst + (size_t)row * 256 + c4) = *(const uint2*)u;
    }
}

// dst = LN(x + y1 + y2)  (split-K combine fused into LN3)
__global__ __launch_bounds__(256) void ln_add3(
    const float* __restrict__ x, const float* __restrict__ y1,
    const float* __restrict__ y2, const float* __restrict__ g,
    const float* __restrict__ bta, float* __restrict__ dst)
{
    int row = blockIdx.x * 4 + (threadIdx.x >> 6);
    int c4 = (threadIdx.x & 63) * 4;
    float4 a = *(const float4*)(x + (size_t)row * 256 + c4);
    float4 b = *(const float4*)(y1 + (size_t)row * 256 + c4);
    float4 d = *(const float4*)(y2 + (size_t)row * 256 + c4);
    float4 v = { a.x + b.x + d.x, a.y + b.y + d.y, a.z + b.z + d.z, a.w + b.w + d.w };
    float sm = v.x + v.y + v.z + v.w;
    float s2 = v.x * v.x + v.y * v.y + v.z * v.z + v.w * v.w;
#pragma unroll
    for (int o = 32; o; o >>= 1) { sm += __shfl_xor(sm, o); s2 += __shfl_xor(s2, o); }
    float mean = sm * (1.f / 256.f);
    float rstd = 1.f / sqrtf(s2 * (1.f / 256.f) - mean * mean + 1e-5f);
    float4 gv = *(const float4*)(g + c4);
    float4 bv = *(const float4*)(bta + c4);
    float4 r = { (v.x - mean) * rstd * gv.x + bv.x, (v.y - mean) * rstd * gv.y + bv.y,
                 (v.z - mean) * rstd * gv.z + bv.z, (v.w - mean) * rstd * gv.w + bv.w };
    *(float4*)(dst + (size_t)row * 256 + c4) = r;
}

// ---------------------------------------------------------------------------
// deformable bilinear sampling + aw-softmax reduce over NP=4 (bf16 out).
// ---------------------------------------------------------------------------
__global__ __launch_bounds__(256) void deform_sample(
    const float* __restrict__ oaw, const float* __restrict__ refb,
    const float* __restrict__ mem, u16* __restrict__ samp)
{
    const int row = blockIdx.x;
    const int b = row / 4800;
    const int tid = threadIdx.x;
    const int h = tid >> 5;
    const float4 rb = *(const float4*)(refb + (size_t)row * 4);
    const float* base = oaw + (size_t)row * 128;
    float a0 = base[64 + h * 4 + 0], a1 = base[64 + h * 4 + 1];
    float a2 = base[64 + h * 4 + 2], a3 = base[64 + h * 4 + 3];
    float am = fmaxf(fmaxf(a0, a1), fmaxf(a2, a3));
    float e0 = __expf(a0 - am), e1 = __expf(a1 - am), e2 = __expf(a2 - am), e3 = __expf(a3 - am);
    float rs = 1.f / (e0 + e1 + e2 + e3);
    float wp[4] = { e0 * rs, e1 * rs, e2 * rs, e3 * rs };
    const float* op = base + h * 8;
    const float* mb = mem + (size_t)b * 16384 * 256 + tid;

    int offs[16];
    float wts[16];
#pragma unroll
    for (int p = 0; p < 4; ++p) {
        float gx = (rb.x + op[p * 2 + 0] * rb.z * 0.5f) * 128.f - 0.5f;
        float gy = (rb.y + op[p * 2 + 1] * rb.w * 0.5f) * 128.f - 0.5f;
        float x0f = floorf(gx), y0f = floorf(gy);
        int x0 = (int)x0f, y0 = (int)y0f;
        float wx1 = gx - x0f, wy1 = gy - y0f;
        float wx0 = 1.f - wx1, wy0 = 1.f - wy1;
        float vx0 = ((unsigned)x0 < 128u) ? 1.f : 0.f;
        float vx1 = ((unsigned)(x0 + 1) < 128u) ? 1.f : 0.f;
        float vy0 = ((unsigned)y0 < 128u) ? 1.f : 0.f;
        float vy1 = ((unsigned)(y0 + 1) < 128u) ? 1.f : 0.f;
        int xc0 = min(max(x0, 0), 127), xc1 = min(max(x0 + 1, 0), 127);
        int yc0 = min(max(y0, 0), 127), yc1 = min(max(y0 + 1, 0), 127);
        offs[p * 4 + 0] = (yc0 * 128 + xc0) << 8;
        offs[p * 4 + 1] = (yc0 * 128 + xc1) << 8;
        offs[p * 4 + 2] = (yc1 * 128 + xc0) << 8;
        offs[p * 4 + 3] = (yc1 * 128 + xc1) << 8;
        wts[p * 4 + 0] = wp[p] * wx0 * wy0 * vx0 * vy0;
        wts[p * 4 + 1] = wp[p] * wx1 * wy0 * vx1 * vy0;
        wts[p * 4 + 2] = wp[p] * wx0 * wy1 * vx0 * vy1;
        wts[p * 4 + 3] = wp[p] * wx1 * wy1 * vx1 * vy1;
    }
    float vals[16];
#pragma unroll
    for (int i = 0; i < 16; ++i) vals[i] = mb[offs[i]];
    float acc = 0.f;
#pragma unroll
    for (int i = 0; i < 16; ++i) acc = fmaf(vals[i], wts[i], acc);
    samp[(size_t)row * 256 + tid] = f2b(acc);
}

extern "C" void kernel_launch(void* const* d_in, const int* in_sizes, int n_in,
                              void* d_out, int out_size, void* d_ws, size_t ws_size,
                              hipStream_t stream) {
    const float* inst_query = (const float*)d_in[0];
    const float* sub_contour = (const float*)d_in[1];
    const float* memory_feats = (const float*)d_in[2];
    const float* ref_boxes = (const float*)d_in[3];
    const float* inst_in_w = (const float*)d_in[4];
    const float* inst_in_b = (const float*)d_in[5];
    const float* inst_out_w = (const float*)d_in[6];
    const float* inst_out_b = (const float*)d_in[7];
    const float* sc_in_w = (const float*)d_in[8];
    const float* sc_in_b = (const float*)d_in[9];
    const float* sc_out_w = (const float*)d_in[10];
    const float* sc_out_b = (const float*)d_in[11];
    const float* off_w = (const float*)d_in[12];
    const float* off_b = (const float*)d_in[13];
    const float* aw_w = (const float*)d_in[14];
    const float* aw_b = (const float*)d_in[15];
    const float* outp_w = (const float*)d_in[16];
    const float* outp_b = (const float*)d_in[17];
    const float* lin1_w = (const float*)d_in[18];
    const float* lin1_b = (const float*)d_in[19];
    const float* lin2_w = (const float*)d_in[20];
    const float* lin2_b = (const float*)d_in[21];
    const float* n1_g = (const float*)d_in[22];
    const float* n1_b = (const float*)d_in[23];
    const float* n2_g = (const float*)d_in[24];
    const float* n2_b = (const float*)d_in[25];
    const float* n3_g = (const float*)d_in[26];
    const float* n3_b = (const float*)d_in[27];

    // ---- workspace layout ----
    u16* wsb = (u16*)d_ws;
    u16* qkv_b   = wsb;                       // 19200*768  = 14,745,600
    u16* xbuf_b  = qkv_b + 14745600;          //  4,915,200
    u16* obuf_b  = xbuf_b + 4915200;          //  4,915,200
    u16* tgt_b   = obuf_b + 4915200;          //  4,915,200
    u16* w_inst_in  = tgt_b + 4915200;        //    196,608
    u16* w_inst_out = w_inst_in + 196608;     //     65,536
    u16* w_sc_in    = w_inst_out + 65536;     //    196,608
    u16* w_sc_out   = w_sc_in + 196608;       //     65,536
    u16* w_outp     = w_sc_out + 65536;       //     65,536
    u16* w_lin1     = w_outp + 65536;         //    524,288
    u16* w_lin2     = w_lin1 + 524288;        //    524,288
    u16* w_offaw    = w_lin2 + 524288;        //     32,768
    u16* ffn1_b = qkv_b;                      // alias (2-chunk fallback)
    u16* instq_b = tgt_b;                     // temp (tgt_b not live yet)
    float* fp    = (float*)(w_offaw + 32768);
    float* insto = fp;                        //    307,200
    float* tgt   = insto + 307200;            //  4,915,200
    float* t2    = tgt + 4915200;             //  4,915,200
    float* oawb  = t2 + 4915200;              //  2,457,600
    float* b_offaw = oawb + 2457600;          //        128
    float* zbias   = b_offaw + 128;           //        256
    // full-FFN scratch: 19200*2048 bf16, then split-K partial t2b (fp32)
    size_t base_bytes = (size_t)((char*)(zbias + 256) - (char*)d_ws);
    size_t ffn_off = (base_bytes + 255) & ~(size_t)255;
    u16* ffn1_full = (u16*)((char*)d_ws + ffn_off);
    float* t2b = (float*)(ffn1_full + 39321600);
    bool full_ffn = ws_size >= ffn_off + (size_t)2 * 19200 * 2048;
    bool split_k  = ws_size >= ffn_off + (size_t)2 * 19200 * 2048 + (size_t)4 * 4915200;

    dim3 blk(256);

    // fused weight/activation conversions
    Cvt8 ca;
    ca.s[0] = { inst_in_w,  w_inst_in,  196608 / 8 };
    ca.s[1] = { inst_out_w, w_inst_out, 65536 / 8 };
    ca.s[2] = { sc_in_w,    w_sc_in,    196608 / 8 };
    ca.s[3] = { sc_out_w,   w_sc_out,   65536 / 8 };
    ca.s[4] = { outp_w,     w_outp,     65536 / 8 };
    ca.s[5] = { lin1_w,     w_lin1,     524288 / 8 };
    ca.s[6] = { lin2_w,     w_lin2,     524288 / 8 };
    ca.s[7] = { inst_query, instq_b,    307200 / 8 };
    int totalv = (196608 * 2 + 65536 * 3 + 524288 * 2 + 307200) / 8;
    cvt_multi<<<(totalv + 255) / 256, blk, 0, stream>>>(ca, totalv);
    pack_offaw<<<128, blk, 0, stream>>>(off_w, off_b, aw_w, aw_b, w_offaw, b_offaw, zbias);

    // 1. inst QKV -> qkv_b (bf16)   [K=256: BK=128]
    gemm_mfma<0,1,128,128><<<dim3(6, 10), blk, 0, stream>>>(instq_b, w_inst_in, inst_in_b, qkv_b, 1200, 768, 256, 256, nullptr, nullptr);
    // 2. inst attention (NBH=32, S=4: tiny K/V, needs grid supply)
    attn_mfma<<<128, blk, 0, stream>>>(qkv_b, obuf_b, 4, 32);
    // 3. inst out-proj -> insto (fp32)
    gemm_mfma<0,0,64,128><<<dim3(2, 19), blk, 0, stream>>>(obuf_b, w_inst_out, inst_out_b, insto, 1200, 256, 256, 256, nullptr, nullptr);
    // 4. sc transpose -> xbuf_b (bf16)
    sc_transpose<<<4800, blk, 0, stream>>>(sub_contour, xbuf_b);
    // 5. sc QKV
    gemm_mfma<0,1,128,128><<<dim3(6, 150), blk, 0, stream>>>(xbuf_b, w_sc_in, sc_in_b, qkv_b, 19200, 768, 256, 256, nullptr, nullptr);
    // 6. sc attention (S=1: one block per (bi,h) — no duplicate K/V staging)
    attn_mfma<<<512, blk, 0, stream>>>(qkv_b, obuf_b, 1, 512);
    // 7. sc out-proj -> t2 (fp32, sc row order)
    gemm_mfma<0,0,64,128><<<dim3(2, 300), blk, 0, stream>>>(obuf_b, w_sc_out, sc_out_b, t2, 19200, 256, 256, 256, nullptr, nullptr);
    // 8. combine + LN1 -> tgt (fp32) + tgt_b (bf16)
    ln1_combine<<<4800, blk, 0, stream>>>(sub_contour, t2, insto, n1_g, n1_b, tgt, tgt_b);
    // 9. packed off+aw projection -> oawb [19200][128]
    gemm_mfma<0,0,64,128><<<dim3(1, 300), blk, 0, stream>>>(tgt_b, w_offaw, b_offaw, oawb, 19200, 128, 256, 256, nullptr, nullptr);
    // 10. deformable sampling -> obuf_b (bf16)
    deform_sample<<<19200, blk, 0, stream>>>(oawb, ref_boxes, memory_feats, obuf_b);
    // 11. outp proj -> t2
    gemm_mfma<0,0,64,128><<<dim3(2, 300), blk, 0, stream>>>(obuf_b, w_outp, outp_b, t2, 19200, 256, 256, 256, nullptr, nullptr);
    // 12. LN2 -> tgt (fp32) + tgt_b (bf16)
    ln_add<<<4800, blk, 0, stream>>>(tgt, t2, n2_g, n2_b, tgt, tgt_b);
    // 13. FFN: lin1 TM=64/BK=128; lin2 split-K x2 in ONE dispatch
    if (full_ffn) {
        gemm_mfma<1,1,64,128><<<dim3(16, 300), blk, 0, stream>>>(tgt_b, w_lin1, lin1_b, ffn1_full, 19200, 2048, 256, 256, nullptr, nullptr);
        if (split_k) {
            gemm_mfma<0,0,64,64><<<dim3(2, 300, 2), blk, 0, stream>>>(ffn1_full, w_lin2, lin2_b, t2, 19200, 256, 1024, 2048, zbias, t2b);
            // 14. LN3 (3-input) -> output
            ln_add3<<<4800, blk, 0, stream>>>(tgt, t2, t2b, n3_g, n3_b, (float*)d_out);
            return;
        }
        gemm_mfma<0,0,64,64><<<dim3(2, 300), blk, 0, stream>>>(ffn1_full, w_lin2, lin2_b, t2, 19200, 256, 2048, 2048, nullptr, nullptr);
    } else {
        for (int c = 0; c < 2; ++c) {
            gemm_mfma<1,1,64,128><<<dim3(16, 150), blk, 0, stream>>>(tgt_b + (size_t)c * 9600 * 256, w_lin1, lin1_b, ffn1_b, 9600, 2048, 256, 256, nullptr, nullptr);
            gemm_mfma<0,0,64,64><<<dim3(2, 150), blk, 0, stream>>>(ffn1_b, w_lin2, lin2_b, t2 + (size_t)c * 9600 * 256, 9600, 256, 2048, 2048, nullptr, nullptr);
        }
    }
    // 14. LN3 -> output fp32 (B, NQ, NC, C)
    ln_add<<<4800, blk, 0, stream>>>(tgt, t2, n3_g, n3_b, (float*)d_out, nullptr);
}

// Round 20
// 281.491 us; speedup vs baseline: 1.0263x; 1.0263x over previous
//
#include <hip/hip_runtime.h>
#include <hip/hip_bf16.h>
#include <math.h>

// B=4, NQ=300, NC=16, C=256, NH=8, NP=4, DFF=2048, H=W=128, Lq=4800, hd=32

typedef unsigned short u16;
typedef unsigned int u32;
typedef __attribute__((ext_vector_type(4))) float f32x4;
typedef __attribute__((ext_vector_type(8))) short s16x8;

__device__ __forceinline__ float b2f(u16 u) {
    union { u32 u; float f; } v; v.u = ((u32)u) << 16; return v.f;
}
__device__ __forceinline__ u16 f2b(float f) {
    union { float f; u32 u; } v; v.f = f;
    u32 r = v.u + 0x7fffu + ((v.u >> 16) & 1u);
    return (u16)(r >> 16);
}
__device__ __forceinline__ u32 pkbf(float a, float b) {
    u32 r;
    asm("v_cvt_pk_bf16_f32 %0, %1, %2" : "=v"(r) : "v"(a), "v"(b));
    return r;
}

#define GLOAD_LDS16(g, l) \
    __builtin_amdgcn_global_load_lds((const __attribute__((address_space(1))) void*)(g), \
                                     (__attribute__((address_space(3))) void*)(l), 16, 0, 0)

// ---------------------------------------------------------------------------
// Fused fp32 -> bf16 conversion over up to 8 segments (all sizes % 8 == 0)
// ---------------------------------------------------------------------------
struct CvtSeg { const float* src; u16* dst; int nv; };  // nv = elems/8
struct Cvt8 { CvtSeg s[8]; };

__global__ __launch_bounds__(256) void cvt_multi(Cvt8 a, int totalv) {
    int v = blockIdx.x * 256 + threadIdx.x;
    if (v >= totalv) return;
    int si = 0;
    while (si < 7 && v >= a.s[si].nv) { v -= a.s[si].nv; ++si; }
    const float* src = a.s[si].src + (size_t)v * 8;
    u16* dst = a.s[si].dst + (size_t)v * 8;
    float4 x = *(const float4*)src;
    float4 y = *(const float4*)(src + 4);
    u16 u[8] = { f2b(x.x), f2b(x.y), f2b(x.z), f2b(x.w),
                 f2b(y.x), f2b(y.y), f2b(y.z), f2b(y.w) };
    *(uint4*)dst = *(const uint4*)u;
}

// pack off_w(64) + aw_w(32) + zeros(32) -> [128][256] bf16, bias -> [128] f32
__global__ __launch_bounds__(256) void pack_offaw(
    const float* __restrict__ off_w, const float* __restrict__ off_b,
    const float* __restrict__ aw_w, const float* __restrict__ aw_b,
    u16* __restrict__ wout, float* __restrict__ bout)
{
    int r = blockIdx.x, c = threadIdx.x;
    float v = 0.f;
    if (r < 64) v = off_w[r * 256 + c];
    else if (r < 96) v = aw_w[(r - 64) * 256 + c];
    wout[r * 256 + c] = f2b(v);
    if (c == 0) bout[r] = (r < 64) ? off_b[r] : (r < 96 ? aw_b[r - 64] : 0.f);
}

// ---------------------------------------------------------------------------
// MFMA bf16 GEMM: C[M,N] = A[M,K] @ W[N,K]^T + bias. Tile TM x 128, BK=64/128.
// Chunk-XOR involution (CR=BK/8 chunks/row): stage cc = p ^ (r&(CR-1)),
// read pc = (kk*4+g) ^ (fr&(CR-1)) — 8 lanes/bank-quad both sides.
// Bijective XCD swizzle (T1/m204). LDS-repacked coalesced bf16 epilogue.
// ---------------------------------------------------------------------------
template<int RELU, int OUTBF16, int TM, int BK>
__global__ __launch_bounds__(256) void gemm_mfma(
    const u16* __restrict__ A, const u16* __restrict__ W,
    const float* __restrict__ bias, void* __restrict__ Cout,
    int M, int N, int K, int LDK)
{
    constexpr int MI = TM / 32;            // row-frags per wave (4 or 2)
    constexpr int CR = BK / 8;             // 16B-chunks per row
    constexpr int CHA = TM * BK / 2048;    // A chunks per thread per step
    constexpr int CHB = 128 * BK / 2048;   // B chunks per thread per step
    __shared__ u16 smem[(TM + 128) * BK];
    u16* Asm = smem;
    u16* Bsm = smem + TM * BK;
    const int tid = threadIdx.x;
    const int wave = tid >> 6, lane = tid & 63;
    // --- bijective XCD swizzle (m204)
    const int gx = gridDim.x;
    const int nwg = gx * gridDim.y;
    const int lid = blockIdx.y * gx + blockIdx.x;
    const int q8 = nwg >> 3, r8 = nwg & 7;
    const int xcd = lid & 7, sub = lid >> 3;
    const int logical = (xcd < r8 ? xcd * (q8 + 1) : r8 * (q8 + 1) + (xcd - r8) * q8) + sub;
    const int bm = (logical / gx) * TM, bn = (logical % gx) * 128;
    const int wr = (wave >> 1) * (TM / 2), wc = (wave & 1) * 64;
    const int fr = lane & 15;
    const int g = lane >> 4;
    const int sw = fr & (CR - 1);
    f32x4 acc[MI][4] = {};

    for (int k0 = 0; k0 < K; k0 += BK) {
        __syncthreads();
#pragma unroll
        for (int c = 0; c < CHA; ++c) {
            int L = c * 256 + tid;              // 16B-chunk id in A tile
            int r = L / CR, p = L % CR;         // row, physical chunk in row
            int cc = p ^ (r & (CR - 1));        // logical k-chunk (involution)
            int ra = bm + r; if (ra >= M) ra = M - 1;
            GLOAD_LDS16(A + (size_t)ra * LDK + k0 + cc * 8, Asm + (c * 256 + wave * 64) * 8);
        }
#pragma unroll
        for (int c = 0; c < CHB; ++c) {
            int L = c * 256 + tid;
            int r = L / CR, p = L % CR;
            int cc = p ^ (r & (CR - 1));
            int rb = bn + r;
            GLOAD_LDS16(W + (size_t)rb * LDK + k0 + cc * 8, Bsm + (c * 256 + wave * 64) * 8);
        }
        __syncthreads();
#pragma unroll
        for (int kk = 0; kk < BK / 32; ++kk) {
            const int pc = (kk * 4 + g) ^ sw;   // physical chunk for this frag
            s16x8 af[MI], bf[4];
#pragma unroll
            for (int i = 0; i < MI; ++i)
                af[i] = *(const s16x8*)(Asm + (wr + i * 16 + fr) * BK + pc * 8);
#pragma unroll
            for (int i = 0; i < 4; ++i)
                bf[i] = *(const s16x8*)(Bsm + (wc + i * 16 + fr) * BK + pc * 8);
#pragma unroll
            for (int mi = 0; mi < MI; ++mi)
#pragma unroll
                for (int ni = 0; ni < 4; ++ni)
                    acc[mi][ni] = __builtin_amdgcn_mfma_f32_16x16x32_bf16(
                        af[mi], bf[ni], acc[mi][ni], 0, 0, 0);
        }
    }
    const int cc = lane & 15, cr4 = (lane >> 4) * 4;
    if (OUTBF16) {
        // repack in 32-row passes: smem[32][136] (272B stride)
#pragma unroll
        for (int p = 0; p < TM / 32; ++p) {
            const int base = p * 32;
            __syncthreads();
#pragma unroll
            for (int mi = 0; mi < MI; ++mi) {
                int rowoff = wr + mi * 16;
                if (rowoff < base || rowoff >= base + 32) continue;
#pragma unroll
                for (int ni = 0; ni < 4; ++ni) {
                    int col = wc + ni * 16 + cc;
                    float bv = bias[bn + col];
#pragma unroll
                    for (int j = 0; j < 4; ++j) {
                        float v = acc[mi][ni][j] + bv;
                        if (RELU) v = fmaxf(v, 0.f);
                        smem[(rowoff - base + cr4 + j) * 136 + col] = f2b(v);
                    }
                }
            }
            __syncthreads();
            for (int t = tid; t < 512; t += 256) {
                int row = t >> 4, ck = t & 15;
                int grow = bm + base + row;
                if (grow < M)
                    *(uint4*)((u16*)Cout + (size_t)grow * N + bn + ck * 8) =
                        *(const uint4*)&smem[row * 136 + ck * 8];
            }
        }
    } else {
#pragma unroll
        for (int mi = 0; mi < MI; ++mi) {
#pragma unroll
            for (int ni = 0; ni < 4; ++ni) {
                int col = bn + wc + ni * 16 + cc;
                float bv = bias[col];
#pragma unroll
                for (int j = 0; j < 4; ++j) {
                    int row = bm + wr + mi * 16 + cr4 + j;
                    if (row >= M) continue;
                    float v = acc[mi][ni][j] + bv;
                    if (RELU) v = fmaxf(v, 0.f);
                    ((float*)Cout)[(size_t)row * N + col] = v;
                }
            }
        }
    }
}

// ---------------------------------------------------------------------------
// MFMA flash attention, swapped-operand, online softmax with 64-key chunks.
// Seg-major block remap (segs of one bh share an XCD). Vt swizzle with
// T4(d>>3): staging u32 writes 2-way; b128 reads 8-lanes/quad.
// ---------------------------------------------------------------------------
#define T4(s) ((((s) << 1) ^ (s)) & 7)   // {0,3,6,5} for s=0..3
#define VIDX(d, k) (((((k) >> 3) ^ ((d) & 7) ^ T4((d) >> 3)) << 3) + ((k) & 7))

__global__ __launch_bounds__(256) void attn_mfma(
    const u16* __restrict__ qkv, u16* __restrict__ O, int S, int NBH)
{
    const int bh = blockIdx.x % NBH, seg = blockIdx.x / NBH;
    const int bi = bh >> 3, h = bh & 7;
    __shared__ u16 Ks[320][40];    // K raw, row-major (80B stride: conflict-free)
    __shared__ u16 Vt[32][320];    // V transposed, XOR-swizzled chunks
    const int tid = threadIdx.x;

    for (int idx = tid; idx < 1200; idx += 256) {
        int k = idx >> 2, sub = idx & 3;
        const u16* kp = qkv + ((size_t)(bi * 300 + k)) * 768 + 256 + h * 32 + sub * 8;
        *(uint4*)&Ks[k][sub * 8] = *(const uint4*)kp;
    }
    for (int idx = tid; idx < 600; idx += 256) {
        int kp2 = idx >> 2, sub = idx & 3;
        int k0 = kp2 * 2;
        const u16* vp = qkv + ((size_t)(bi * 300 + k0)) * 768 + 512 + h * 32 + sub * 8;
        uint4 v0 = *(const uint4*)vp;
        uint4 v1 = *(const uint4*)(vp + 768);
        u16 a0[8], a1[8];
        *(uint4*)a0 = v0; *(uint4*)a1 = v1;
#pragma unroll
        for (int j = 0; j < 8; ++j) {
            int d = sub * 8 + j;
            *(u32*)&Vt[d][VIDX(d, k0)] = (u32)a0[j] | ((u32)a1[j] << 16);
        }
    }
    for (int idx = tid; idx < 320; idx += 256) {
        int d = idx & 31, k0 = 300 + (idx >> 5) * 2;
        *(u32*)&Vt[d][VIDX(d, k0)] = 0;
    }
    __syncthreads();

    const int lane = tid & 63, wave = tid >> 6;
    const int c = lane & 15, g = lane >> 4;
    const int fk = g * 8;
    const f32x4 zero = { 0.f, 0.f, 0.f, 0.f };
    const float SCL2 = 0.25505416f;           // (1/sqrt(32)) * log2(e)
    const int sA = c + ((g & 1) << 5);
    const int sB = sA + 16;
    const bool hi = g >= 2;

    for (int qt = seg * 4 + wave; qt < 19; qt += 4 * S) {
        int qrow = qt * 16 + c; if (qrow > 299) qrow = 299;
        s16x8 afq = *(const s16x8*)(qkv + ((size_t)(bi * 300 + qrow)) * 768 + h * 32 + fk);
        f32x4 acc0 = zero, acc1 = zero;
        float m = -1e30f, l = 0.f;

        for (int kc = 0; kc < 5; ++kc) {
            const int kb = kc * 64;
            s16x8 ak0 = *(const s16x8*)&Ks[kb + c][fk];
            s16x8 ak1 = *(const s16x8*)&Ks[kb + 16 + c][fk];
            s16x8 ak2 = *(const s16x8*)&Ks[kb + 32 + c][fk];
            s16x8 ak3 = *(const s16x8*)&Ks[kb + 48 + c][fk];
            __builtin_amdgcn_s_setprio(1);
            f32x4 s0 = __builtin_amdgcn_mfma_f32_16x16x32_bf16(ak0, afq, zero, 0, 0, 0);
            f32x4 s1 = __builtin_amdgcn_mfma_f32_16x16x32_bf16(ak1, afq, zero, 0, 0, 0);
            f32x4 s2 = __builtin_amdgcn_mfma_f32_16x16x32_bf16(ak2, afq, zero, 0, 0, 0);
            f32x4 s3 = __builtin_amdgcn_mfma_f32_16x16x32_bf16(ak3, afq, zero, 0, 0, 0);
            __builtin_amdgcn_s_setprio(0);
            if (kb == 256) {   // keys >= 300 invalid (overwrite kills NaN)
#pragma unroll
                for (int j = 0; j < 4; ++j) {
                    if (g == 3) s2[j] = -1e30f;
                    s3[j] = -1e30f;
                }
            }
            float cm = fmaxf(fmaxf(fmaxf(s0[0], s0[1]), fmaxf(s0[2], s0[3])),
                             fmaxf(fmaxf(s1[0], s1[1]), fmaxf(s1[2], s1[3])));
            float cm2 = fmaxf(fmaxf(fmaxf(s2[0], s2[1]), fmaxf(s2[2], s2[3])),
                              fmaxf(fmaxf(s3[0], s3[1]), fmaxf(s3[2], s3[3])));
            cm = fmaxf(cm, cm2);
            cm = fmaxf(cm, __shfl_xor(cm, 16));
            cm = fmaxf(cm, __shfl_xor(cm, 32));
            float mn = fmaxf(m, cm);
            float corr = exp2f((m - mn) * SCL2);
            m = mn;
            float p0[4], p1[4], p2[4], p3[4];
#pragma unroll
            for (int j = 0; j < 4; ++j) {
                p0[j] = exp2f((s0[j] - m) * SCL2);
                p1[j] = exp2f((s1[j] - m) * SCL2);
                p2[j] = exp2f((s2[j] - m) * SCL2);
                p3[j] = exp2f((s3[j] - m) * SCL2);
            }
            float cs = ((p0[0] + p0[1]) + (p0[2] + p0[3]))
                     + ((p1[0] + p1[1]) + (p1[2] + p1[3]))
                     + ((p2[0] + p2[1]) + (p2[2] + p2[3]))
                     + ((p3[0] + p3[1]) + (p3[2] + p3[3]));
            cs += __shfl_xor(cs, 16);
            cs += __shfl_xor(cs, 32);
            l = l * corr + cs;
            u32 w0 = pkbf(p0[0], p0[1]), w1 = pkbf(p0[2], p0[3]);
            u32 w2 = pkbf(p1[0], p1[1]), w3 = pkbf(p1[2], p1[3]);
            u32 w4 = pkbf(p2[0], p2[1]), w5 = pkbf(p2[2], p2[3]);
            u32 w6 = pkbf(p3[0], p3[1]), w7 = pkbf(p3[2], p3[3]);
            int x0 = __shfl((int)w0, sA), x1 = __shfl((int)w1, sA);
            int x2 = __shfl((int)w2, sA), x3 = __shfl((int)w3, sA);
            int y0 = __shfl((int)w0, sB), y1 = __shfl((int)w1, sB);
            int y2 = __shfl((int)w2, sB), y3 = __shfl((int)w3, sB);
            union { u32 w[4]; s16x8 v; } afpA;
            afpA.w[0] = hi ? (u32)x2 : (u32)x0;
            afpA.w[1] = hi ? (u32)x3 : (u32)x1;
            afpA.w[2] = hi ? (u32)y2 : (u32)y0;
            afpA.w[3] = hi ? (u32)y3 : (u32)y1;
            int x4 = __shfl((int)w4, sA), x5 = __shfl((int)w5, sA);
            int x6 = __shfl((int)w6, sA), x7 = __shfl((int)w7, sA);
            int y4 = __shfl((int)w4, sB), y5 = __shfl((int)w5, sB);
            int y6 = __shfl((int)w6, sB), y7 = __shfl((int)w7, sB);
            union { u32 w[4]; s16x8 v; } afpB;
            afpB.w[0] = hi ? (u32)x6 : (u32)x4;
            afpB.w[1] = hi ? (u32)x7 : (u32)x5;
            afpB.w[2] = hi ? (u32)y6 : (u32)y4;
            afpB.w[3] = hi ? (u32)y7 : (u32)y5;
            float c0 = __shfl(corr, g * 4 + 0), c1 = __shfl(corr, g * 4 + 1);
            float c2 = __shfl(corr, g * 4 + 2), c3 = __shfl(corr, g * 4 + 3);
            acc0[0] *= c0; acc0[1] *= c1; acc0[2] *= c2; acc0[3] *= c3;
            acc1[0] *= c0; acc1[1] *= c1; acc1[2] *= c2; acc1[3] *= c3;
            s16x8 bv0 = *(const s16x8*)&Vt[c][VIDX(c, kb + fk)];
            s16x8 bv1 = *(const s16x8*)&Vt[16 + c][VIDX(16 + c, kb + fk)];
            s16x8 bv2 = *(const s16x8*)&Vt[c][VIDX(c, kb + 32 + fk)];
            s16x8 bv3 = *(const s16x8*)&Vt[16 + c][VIDX(16 + c, kb + 32 + fk)];
            __builtin_amdgcn_s_setprio(1);
            acc0 = __builtin_amdgcn_mfma_f32_16x16x32_bf16(afpA.v, bv0, acc0, 0, 0, 0);
            acc1 = __builtin_amdgcn_mfma_f32_16x16x32_bf16(afpA.v, bv1, acc1, 0, 0, 0);
            acc0 = __builtin_amdgcn_mfma_f32_16x16x32_bf16(afpB.v, bv2, acc0, 0, 0, 0);
            acc1 = __builtin_amdgcn_mfma_f32_16x16x32_bf16(afpB.v, bv3, acc1, 0, 0, 0);
            __builtin_amdgcn_s_setprio(0);
        }
        float l0 = __shfl(l, g * 4 + 0), l1 = __shfl(l, g * 4 + 1);
        float l2 = __shfl(l, g * 4 + 2), l3 = __shfl(l, g * 4 + 3);
        float lj[4] = { l0, l1, l2, l3 };
#pragma unroll
        for (int j = 0; j < 4; ++j) {
            int q = qt * 16 + g * 4 + j;
            if (q < 300) {
                float r = 1.f / lj[j];
                u16* op = O + ((size_t)(bi * 300 + q)) * 256 + h * 32;
                op[c]      = f2b(acc0[j] * r);
                op[16 + c] = f2b(acc1[j] * r);
            }
        }
    }
}

// sc_x[(b*16+nc)*300+nq][c] = sub_contour_query[b][nq][nc][c]  (bf16 out)
__global__ __launch_bounds__(256) void sc_transpose(
    const float* __restrict__ scq, u16* __restrict__ out)
{
    int row = blockIdx.x * 4 + (threadIdx.x >> 6);
    int c4 = (threadIdx.x & 63) * 4;
    int b = row / 4800;
    int rem = row % 4800;
    int nc = rem / 300, nq = rem % 300;
    float4 v = *(const float4*)(scq + ((size_t)((b * 300 + nq) * 16 + nc)) * 256 + c4);
    u16 u[4] = { f2b(v.x), f2b(v.y), f2b(v.z), f2b(v.w) };
    *(uint2*)(out + (size_t)row * 256 + c4) = *(const uint2*)u;
}

// tgt = LN( scq + 2*(sc_o + inst_o) ); 4 rows/block, row == wave, no LDS
__global__ __launch_bounds__(256) void ln1_combine(
    const float* __restrict__ scq, const float* __restrict__ sco,
    const float* __restrict__ insto, const float* __restrict__ g,
    const float* __restrict__ bta, float* __restrict__ tgt,
    u16* __restrict__ tgtb)
{
    int row = blockIdx.x * 4 + (threadIdx.x >> 6);
    int c4 = (threadIdx.x & 63) * 4;
    int b = row / 4800;
    int rem = row % 4800;
    int nq = rem >> 4, nc = rem & 15;
    float4 a = *(const float4*)(scq + (size_t)row * 256 + c4);
    float4 s = *(const float4*)(sco + ((size_t)((b * 16 + nc) * 300 + nq)) * 256 + c4);
    float4 i = *(const float4*)(insto + ((size_t)(b * 300 + nq)) * 256 + c4);
    float4 v = { a.x + 2.f * (s.x + i.x), a.y + 2.f * (s.y + i.y),
                 a.z + 2.f * (s.z + i.z), a.w + 2.f * (s.w + i.w) };
    float sm = v.x + v.y + v.z + v.w;
    float s2 = v.x * v.x + v.y * v.y + v.z * v.z + v.w * v.w;
#pragma unroll
    for (int o = 32; o; o >>= 1) { sm += __shfl_xor(sm, o); s2 += __shfl_xor(s2, o); }
    float mean = sm * (1.f / 256.f);
    float rstd = 1.f / sqrtf(s2 * (1.f / 256.f) - mean * mean + 1e-5f);
    float4 gv = *(const float4*)(g + c4);
    float4 bv = *(const float4*)(bta + c4);
    float4 r = { (v.x - mean) * rstd * gv.x + bv.x, (v.y - mean) * rstd * gv.y + bv.y,
                 (v.z - mean) * rstd * gv.z + bv.z, (v.w - mean) * rstd * gv.w + bv.w };
    *(float4*)(tgt + (size_t)row * 256 + c4) = r;
    u16 u[4] = { f2b(r.x), f2b(r.y), f2b(r.z), f2b(r.w) };
    *(uint2*)(tgtb + (size_t)row * 256 + c4) = *(const uint2*)u;
}

// dst = LN(x + y); optional bf16 copy; 4 rows/block, row == wave, no LDS
__global__ __launch_bounds__(256) void ln_add(
    const float* __restrict__ x, const float* __restrict__ y,
    const float* __restrict__ g, const float* __restrict__ bta,
    float* __restrict__ dst, u16* __restrict__ bdst)
{
    int row = blockIdx.x * 4 + (threadIdx.x >> 6);
    int c4 = (threadIdx.x & 63) * 4;
    float4 a = *(const float4*)(x + (size_t)row * 256 + c4);
    float4 b = *(const float4*)(y + (size_t)row * 256 + c4);
    float4 v = { a.x + b.x, a.y + b.y, a.z + b.z, a.w + b.w };
    float sm = v.x + v.y + v.z + v.w;
    float s2 = v.x * v.x + v.y * v.y + v.z * v.z + v.w * v.w;
#pragma unroll
    for (int o = 32; o; o >>= 1) { sm += __shfl_xor(sm, o); s2 += __shfl_xor(s2, o); }
    float mean = sm * (1.f / 256.f);
    float rstd = 1.f / sqrtf(s2 * (1.f / 256.f) - mean * mean + 1e-5f);
    float4 gv = *(const float4*)(g + c4);
    float4 bv = *(const float4*)(bta + c4);
    float4 r = { (v.x - mean) * rstd * gv.x + bv.x, (v.y - mean) * rstd * gv.y + bv.y,
                 (v.z - mean) * rstd * gv.z + bv.z, (v.w - mean) * rstd * gv.w + bv.w };
    *(float4*)(dst + (size_t)row * 256 + c4) = r;
    if (bdst) {
        u16 u[4] = { f2b(r.x), f2b(r.y), f2b(r.z), f2b(r.w) };
        *(uint2*)(bdst + (size_t)row * 256 + c4) = *(const uint2*)u;
    }
}

// ---------------------------------------------------------------------------
// deformable bilinear sampling + aw-softmax reduce over NP=4 (bf16 out).
// ---------------------------------------------------------------------------
__global__ __launch_bounds__(256) void deform_sample(
    const float* __restrict__ oaw, const float* __restrict__ refb,
    const float* __restrict__ mem, u16* __restrict__ samp)
{
    const int row = blockIdx.x;
    const int b = row / 4800;
    const int tid = threadIdx.x;
    const int h = tid >> 5;
    const float4 rb = *(const float4*)(refb + (size_t)row * 4);
    const float* base = oaw + (size_t)row * 128;
    float a0 = base[64 + h * 4 + 0], a1 = base[64 + h * 4 + 1];
    float a2 = base[64 + h * 4 + 2], a3 = base[64 + h * 4 + 3];
    float am = fmaxf(fmaxf(a0, a1), fmaxf(a2, a3));
    float e0 = __expf(a0 - am), e1 = __expf(a1 - am), e2 = __expf(a2 - am), e3 = __expf(a3 - am);
    float rs = 1.f / (e0 + e1 + e2 + e3);
    float wp[4] = { e0 * rs, e1 * rs, e2 * rs, e3 * rs };
    const float* op = base + h * 8;
    const float* mb = mem + (size_t)b * 16384 * 256 + tid;

    int offs[16];
    float wts[16];
#pragma unroll
    for (int p = 0; p < 4; ++p) {
        float gx = (rb.x + op[p * 2 + 0] * rb.z * 0.5f) * 128.f - 0.5f;
        float gy = (rb.y + op[p * 2 + 1] * rb.w * 0.5f) * 128.f - 0.5f;
        float x0f = floorf(gx), y0f = floorf(gy);
        int x0 = (int)x0f, y0 = (int)y0f;
        float wx1 = gx - x0f, wy1 = gy - y0f;
        float wx0 = 1.f - wx1, wy0 = 1.f - wy1;
        float vx0 = ((unsigned)x0 < 128u) ? 1.f : 0.f;
        float vx1 = ((unsigned)(x0 + 1) < 128u) ? 1.f : 0.f;
        float vy0 = ((unsigned)y0 < 128u) ? 1.f : 0.f;
        float vy1 = ((unsigned)(y0 + 1) < 128u) ? 1.f : 0.f;
        int xc0 = min(max(x0, 0), 127), xc1 = min(max(x0 + 1, 0), 127);
        int yc0 = min(max(y0, 0), 127), yc1 = min(max(y0 + 1, 0), 127);
        offs[p * 4 + 0] = (yc0 * 128 + xc0) << 8;
        offs[p * 4 + 1] = (yc0 * 128 + xc1) << 8;
        offs[p * 4 + 2] = (yc1 * 128 + xc0) << 8;
        offs[p * 4 + 3] = (yc1 * 128 + xc1) << 8;
        wts[p * 4 + 0] = wp[p] * wx0 * wy0 * vx0 * vy0;
        wts[p * 4 + 1] = wp[p] * wx1 * wy0 * vx1 * vy0;
        wts[p * 4 + 2] = wp[p] * wx0 * wy1 * vx0 * vy1;
        wts[p * 4 + 3] = wp[p] * wx1 * wy1 * vx1 * vy1;
    }
    float vals[16];
#pragma unroll
    for (int i = 0; i < 16; ++i) vals[i] = mb[offs[i]];
    float acc = 0.f;
#pragma unroll
    for (int i = 0; i < 16; ++i) acc = fmaf(vals[i], wts[i], acc);
    samp[(size_t)row * 256 + tid] = f2b(acc);
}

extern "C" void kernel_launch(void* const* d_in, const int* in_sizes, int n_in,
                              void* d_out, int out_size, void* d_ws, size_t ws_size,
                              hipStream_t stream) {
    const float* inst_query = (const float*)d_in[0];
    const float* sub_contour = (const float*)d_in[1];
    const float* memory_feats = (const float*)d_in[2];
    const float* ref_boxes = (const float*)d_in[3];
    const float* inst_in_w = (const float*)d_in[4];
    const float* inst_in_b = (const float*)d_in[5];
    const float* inst_out_w = (const float*)d_in[6];
    const float* inst_out_b = (const float*)d_in[7];
    const float* sc_in_w = (const float*)d_in[8];
    const float* sc_in_b = (const float*)d_in[9];
    const float* sc_out_w = (const float*)d_in[10];
    const float* sc_out_b = (const float*)d_in[11];
    const float* off_w = (const float*)d_in[12];
    const float* off_b = (const float*)d_in[13];
    const float* aw_w = (const float*)d_in[14];
    const float* aw_b = (const float*)d_in[15];
    const float* outp_w = (const float*)d_in[16];
    const float* outp_b = (const float*)d_in[17];
    const float* lin1_w = (const float*)d_in[18];
    const float* lin1_b = (const float*)d_in[19];
    const float* lin2_w = (const float*)d_in[20];
    const float* lin2_b = (const float*)d_in[21];
    const float* n1_g = (const float*)d_in[22];
    const float* n1_b = (const float*)d_in[23];
    const float* n2_g = (const float*)d_in[24];
    const float* n2_b = (const float*)d_in[25];
    const float* n3_g = (const float*)d_in[26];
    const float* n3_b = (const float*)d_in[27];

    // ---- workspace layout ----
    u16* wsb = (u16*)d_ws;
    u16* qkv_b   = wsb;                       // 19200*768  = 14,745,600
    u16* xbuf_b  = qkv_b + 14745600;          //  4,915,200
    u16* obuf_b  = xbuf_b + 4915200;          //  4,915,200
    u16* tgt_b   = obuf_b + 4915200;          //  4,915,200
    u16* w_inst_in  = tgt_b + 4915200;        //    196,608
    u16* w_inst_out = w_inst_in + 196608;     //     65,536
    u16* w_sc_in    = w_inst_out + 65536;     //    196,608
    u16* w_sc_out   = w_sc_in + 196608;       //     65,536
    u16* w_outp     = w_sc_out + 65536;       //     65,536
    u16* w_lin1     = w_outp + 65536;         //    524,288
    u16* w_lin2     = w_lin1 + 524288;        //    524,288
    u16* w_offaw    = w_lin2 + 524288;        //     32,768
    u16* ffn1_b = qkv_b;                      // alias (2-chunk fallback)
    u16* instq_b = tgt_b;                     // temp (tgt_b not live yet)
    float* fp    = (float*)(w_offaw + 32768);
    float* insto = fp;                        //    307,200
    float* tgt   = insto + 307200;            //  4,915,200
    float* t2    = tgt + 4915200;             //  4,915,200
    float* oawb  = t2 + 4915200;              //  2,457,600
    float* b_offaw = oawb + 2457600;          //        128
    // full-FFN scratch (if workspace allows): 19200*2048 bf16 after base
    size_t base_bytes = (size_t)((char*)(b_offaw + 128) - (char*)d_ws);
    size_t ffn_off = (base_bytes + 255) & ~(size_t)255;
    u16* ffn1_full = (u16*)((char*)d_ws + ffn_off);
    bool full_ffn = ws_size >= ffn_off + (size_t)2 * 19200 * 2048;

    dim3 blk(256);

    // fused weight/activation conversions
    Cvt8 ca;
    ca.s[0] = { inst_in_w,  w_inst_in,  196608 / 8 };
    ca.s[1] = { inst_out_w, w_inst_out, 65536 / 8 };
    ca.s[2] = { sc_in_w,    w_sc_in,    196608 / 8 };
    ca.s[3] = { sc_out_w,   w_sc_out,   65536 / 8 };
    ca.s[4] = { outp_w,     w_outp,     65536 / 8 };
    ca.s[5] = { lin1_w,     w_lin1,     524288 / 8 };
    ca.s[6] = { lin2_w,     w_lin2,     524288 / 8 };
    ca.s[7] = { inst_query, instq_b,    307200 / 8 };
    int totalv = (196608 * 2 + 65536 * 3 + 524288 * 2 + 307200) / 8;
    cvt_multi<<<(totalv + 255) / 256, blk, 0, stream>>>(ca, totalv);
    pack_offaw<<<128, blk, 0, stream>>>(off_w, off_b, aw_w, aw_b, w_offaw, b_offaw);

    // 1. inst QKV -> qkv_b (bf16)   [K=256: BK=128]
    gemm_mfma<0,1,128,128><<<dim3(6, 10), blk, 0, stream>>>(instq_b, w_inst_in, inst_in_b, qkv_b, 1200, 768, 256, 256);
    // 2. inst attention (NBH=32, S=4)
    attn_mfma<<<128, blk, 0, stream>>>(qkv_b, obuf_b, 4, 32);
    // 3. inst out-proj -> insto (fp32)
    gemm_mfma<0,0,64,128><<<dim3(2, 19), blk, 0, stream>>>(obuf_b, w_inst_out, inst_out_b, insto, 1200, 256, 256, 256);
    // 4. sc transpose -> xbuf_b (bf16)
    sc_transpose<<<4800, blk, 0, stream>>>(sub_contour, xbuf_b);
    // 5. sc QKV
    gemm_mfma<0,1,128,128><<<dim3(6, 150), blk, 0, stream>>>(xbuf_b, w_sc_in, sc_in_b, qkv_b, 19200, 768, 256, 256);
    // 6. sc attention (S=2, NBH=512 seg-major — best-measured config)
    attn_mfma<<<1024, blk, 0, stream>>>(qkv_b, obuf_b, 2, 512);
    // 7. sc out-proj -> t2 (fp32, sc row order)
    gemm_mfma<0,0,64,128><<<dim3(2, 300), blk, 0, stream>>>(obuf_b, w_sc_out, sc_out_b, t2, 19200, 256, 256, 256);
    // 8. combine + LN1 -> tgt (fp32) + tgt_b (bf16)
    ln1_combine<<<4800, blk, 0, stream>>>(sub_contour, t2, insto, n1_g, n1_b, tgt, tgt_b);
    // 9. packed off+aw projection -> oawb [19200][128]
    gemm_mfma<0,0,64,128><<<dim3(1, 300), blk, 0, stream>>>(tgt_b, w_offaw, b_offaw, oawb, 19200, 128, 256, 256);
    // 10. deformable sampling -> obuf_b (bf16)
    deform_sample<<<19200, blk, 0, stream>>>(oawb, ref_boxes, memory_feats, obuf_b);
    // 11. outp proj -> t2
    gemm_mfma<0,0,64,128><<<dim3(2, 300), blk, 0, stream>>>(obuf_b, w_outp, outp_b, t2, 19200, 256, 256, 256);
    // 12. LN2 -> tgt (fp32) + tgt_b (bf16)
    ln_add<<<4800, blk, 0, stream>>>(tgt, t2, n2_g, n2_b, tgt, tgt_b);
    // 13. FFN: lin1 TM=64/BK=128 (per-dispatch best: 47.2us); lin2 plain BK=64
    //     single dispatch (split-K glue cost more than its TLP gain).
    if (full_ffn) {
        gemm_mfma<1,1,64,128><<<dim3(16, 300), blk, 0, stream>>>(tgt_b, w_lin1, lin1_b, ffn1_full, 19200, 2048, 256, 256);
        gemm_mfma<0,0,64,64><<<dim3(2, 300), blk, 0, stream>>>(ffn1_full, w_lin2, lin2_b, t2, 19200, 256, 2048, 2048);
    } else {
        for (int c = 0; c < 2; ++c) {
            gemm_mfma<1,1,64,128><<<dim3(16, 150), blk, 0, stream>>>(tgt_b + (size_t)c * 9600 * 256, w_lin1, lin1_b, ffn1_b, 9600, 2048, 256, 256);
            gemm_mfma<0,0,64,64><<<dim3(2, 150), blk, 0, stream>>>(ffn1_b, w_lin2, lin2_b, t2 + (size_t)c * 9600 * 256, 9600, 256, 2048, 2048);
        }
    }
    // 14. LN3 -> output fp32 (B, NQ, NC, C)
    ln_add<<<4800, blk, 0, stream>>>(tgt, t2, n3_g, n3_b, (float*)d_out, nullptr);
}

// Round 21
// 281.125 us; speedup vs baseline: 1.0276x; 1.0013x over previous
//
#include <hip/hip_runtime.h>
#include <hip/hip_bf16.h>
#include <math.h>

// B=4, NQ=300, NC=16, C=256, NH=8, NP=4, DFF=2048, H=W=128, Lq=4800, hd=32

typedef unsigned short u16;
typedef unsigned int u32;
typedef __attribute__((ext_vector_type(4))) float f32x4;
typedef __attribute__((ext_vector_type(8))) short s16x8;

__device__ __forceinline__ float b2f(u16 u) {
    union { u32 u; float f; } v; v.u = ((u32)u) << 16; return v.f;
}
__device__ __forceinline__ u16 f2b(float f) {
    union { float f; u32 u; } v; v.f = f;
    u32 r = v.u + 0x7fffu + ((v.u >> 16) & 1u);
    return (u16)(r >> 16);
}
__device__ __forceinline__ u32 pkbf(float a, float b) {
    u32 r;
    asm("v_cvt_pk_bf16_f32 %0, %1, %2" : "=v"(r) : "v"(a), "v"(b));
    return r;
}

#define GLOAD_LDS16(g, l) \
    __builtin_amdgcn_global_load_lds((const __attribute__((address_space(1))) void*)(g), \
                                     (__attribute__((address_space(3))) void*)(l), 16, 0, 0)

// ---------------------------------------------------------------------------
// Fused fp32 -> bf16 conversion over up to 8 segments (all sizes % 8 == 0)
// ---------------------------------------------------------------------------
struct CvtSeg { const float* src; u16* dst; int nv; };  // nv = elems/8
struct Cvt8 { CvtSeg s[8]; };

__global__ __launch_bounds__(256) void cvt_multi(Cvt8 a, int totalv) {
    int v = blockIdx.x * 256 + threadIdx.x;
    if (v >= totalv) return;
    int si = 0;
    while (si < 7 && v >= a.s[si].nv) { v -= a.s[si].nv; ++si; }
    const float* src = a.s[si].src + (size_t)v * 8;
    u16* dst = a.s[si].dst + (size_t)v * 8;
    float4 x = *(const float4*)src;
    float4 y = *(const float4*)(src + 4);
    u16 u[8] = { f2b(x.x), f2b(x.y), f2b(x.z), f2b(x.w),
                 f2b(y.x), f2b(y.y), f2b(y.z), f2b(y.w) };
    *(uint4*)dst = *(const uint4*)u;
}

// pack off_w(64) + aw_w(32) + zeros(32) -> [128][256] bf16, bias -> [128] f32
__global__ __launch_bounds__(256) void pack_offaw(
    const float* __restrict__ off_w, const float* __restrict__ off_b,
    const float* __restrict__ aw_w, const float* __restrict__ aw_b,
    u16* __restrict__ wout, float* __restrict__ bout)
{
    int r = blockIdx.x, c = threadIdx.x;
    float v = 0.f;
    if (r < 64) v = off_w[r * 256 + c];
    else if (r < 96) v = aw_w[(r - 64) * 256 + c];
    wout[r * 256 + c] = f2b(v);
    if (c == 0) bout[r] = (r < 64) ? off_b[r] : (r < 96 ? aw_b[r - 64] : 0.f);
}

// ---------------------------------------------------------------------------
// MFMA bf16 GEMM: C[M,N] = A[M,K] @ W[N,K]^T + bias. Tile TM x 128, BK=64/128.
// Chunk-XOR involution (CR=BK/8 chunks/row): stage cc = p ^ (r&(CR-1)),
// read pc = (kk*4+g) ^ (fr&(CR-1)) — 8 lanes/bank-quad both sides.
// Bijective XCD swizzle (T1/m204). LDS-repacked coalesced bf16 epilogue.
// ---------------------------------------------------------------------------
template<int RELU, int OUTBF16, int TM, int BK>
__global__ __launch_bounds__(256) void gemm_mfma(
    const u16* __restrict__ A, const u16* __restrict__ W,
    const float* __restrict__ bias, void* __restrict__ Cout,
    int M, int N, int K, int LDK)
{
    constexpr int MI = TM / 32;            // row-frags per wave (4 or 2)
    constexpr int CR = BK / 8;             // 16B-chunks per row
    constexpr int CHA = TM * BK / 2048;    // A chunks per thread per step
    constexpr int CHB = 128 * BK / 2048;   // B chunks per thread per step
    __shared__ u16 smem[(TM + 128) * BK];
    u16* Asm = smem;
    u16* Bsm = smem + TM * BK;
    const int tid = threadIdx.x;
    const int wave = tid >> 6, lane = tid & 63;
    // --- bijective XCD swizzle (m204)
    const int gx = gridDim.x;
    const int nwg = gx * gridDim.y;
    const int lid = blockIdx.y * gx + blockIdx.x;
    const int q8 = nwg >> 3, r8 = nwg & 7;
    const int xcd = lid & 7, sub = lid >> 3;
    const int logical = (xcd < r8 ? xcd * (q8 + 1) : r8 * (q8 + 1) + (xcd - r8) * q8) + sub;
    const int bm = (logical / gx) * TM, bn = (logical % gx) * 128;
    const int wr = (wave >> 1) * (TM / 2), wc = (wave & 1) * 64;
    const int fr = lane & 15;
    const int g = lane >> 4;
    const int sw = fr & (CR - 1);
    f32x4 acc[MI][4] = {};

    for (int k0 = 0; k0 < K; k0 += BK) {
        __syncthreads();
#pragma unroll
        for (int c = 0; c < CHA; ++c) {
            int L = c * 256 + tid;              // 16B-chunk id in A tile
            int r = L / CR, p = L % CR;         // row, physical chunk in row
            int cc = p ^ (r & (CR - 1));        // logical k-chunk (involution)
            int ra = bm + r; if (ra >= M) ra = M - 1;
            GLOAD_LDS16(A + (size_t)ra * LDK + k0 + cc * 8, Asm + (c * 256 + wave * 64) * 8);
        }
#pragma unroll
        for (int c = 0; c < CHB; ++c) {
            int L = c * 256 + tid;
            int r = L / CR, p = L % CR;
            int cc = p ^ (r & (CR - 1));
            int rb = bn + r;
            GLOAD_LDS16(W + (size_t)rb * LDK + k0 + cc * 8, Bsm + (c * 256 + wave * 64) * 8);
        }
        __syncthreads();
#pragma unroll
        for (int kk = 0; kk < BK / 32; ++kk) {
            const int pc = (kk * 4 + g) ^ sw;   // physical chunk for this frag
            s16x8 af[MI], bf[4];
#pragma unroll
            for (int i = 0; i < MI; ++i)
                af[i] = *(const s16x8*)(Asm + (wr + i * 16 + fr) * BK + pc * 8);
#pragma unroll
            for (int i = 0; i < 4; ++i)
                bf[i] = *(const s16x8*)(Bsm + (wc + i * 16 + fr) * BK + pc * 8);
#pragma unroll
            for (int mi = 0; mi < MI; ++mi)
#pragma unroll
                for (int ni = 0; ni < 4; ++ni)
                    acc[mi][ni] = __builtin_amdgcn_mfma_f32_16x16x32_bf16(
                        af[mi], bf[ni], acc[mi][ni], 0, 0, 0);
        }
    }
    const int cc = lane & 15, cr4 = (lane >> 4) * 4;
    if (OUTBF16) {
        // repack in 32-row passes: smem[32][136] (272B stride)
#pragma unroll
        for (int p = 0; p < TM / 32; ++p) {
            const int base = p * 32;
            __syncthreads();
#pragma unroll
            for (int mi = 0; mi < MI; ++mi) {
                int rowoff = wr + mi * 16;
                if (rowoff < base || rowoff >= base + 32) continue;
#pragma unroll
                for (int ni = 0; ni < 4; ++ni) {
                    int col = wc + ni * 16 + cc;
                    float bv = bias[bn + col];
#pragma unroll
                    for (int j = 0; j < 4; ++j) {
                        float v = acc[mi][ni][j] + bv;
                        if (RELU) v = fmaxf(v, 0.f);
                        smem[(rowoff - base + cr4 + j) * 136 + col] = f2b(v);
                    }
                }
            }
            __syncthreads();
            for (int t = tid; t < 512; t += 256) {
                int row = t >> 4, ck = t & 15;
                int grow = bm + base + row;
                if (grow < M)
                    *(uint4*)((u16*)Cout + (size_t)grow * N + bn + ck * 8) =
                        *(const uint4*)&smem[row * 136 + ck * 8];
            }
        }
    } else {
#pragma unroll
        for (int mi = 0; mi < MI; ++mi) {
#pragma unroll
            for (int ni = 0; ni < 4; ++ni) {
                int col = bn + wc + ni * 16 + cc;
                float bv = bias[col];
#pragma unroll
                for (int j = 0; j < 4; ++j) {
                    int row = bm + wr + mi * 16 + cr4 + j;
                    if (row >= M) continue;
                    float v = acc[mi][ni][j] + bv;
                    if (RELU) v = fmaxf(v, 0.f);
                    ((float*)Cout)[(size_t)row * N + col] = v;
                }
            }
        }
    }
}

// ---------------------------------------------------------------------------
// MFMA flash attention, swapped-operand, online softmax with 64-key chunks.
// Seg-major block remap (segs of one bh share an XCD). Vt swizzle with
// T4(d>>3): staging u32 writes 2-way; b128 reads 8-lanes/quad.
// ---------------------------------------------------------------------------
#define T4(s) ((((s) << 1) ^ (s)) & 7)   // {0,3,6,5} for s=0..3
#define VIDX(d, k) (((((k) >> 3) ^ ((d) & 7) ^ T4((d) >> 3)) << 3) + ((k) & 7))

__global__ __launch_bounds__(256) void attn_mfma(
    const u16* __restrict__ qkv, u16* __restrict__ O, int S, int NBH)
{
    const int bh = blockIdx.x % NBH, seg = blockIdx.x / NBH;
    const int bi = bh >> 3, h = bh & 7;
    __shared__ u16 Ks[320][40];    // K raw, row-major (80B stride: conflict-free)
    __shared__ u16 Vt[32][320];    // V transposed, XOR-swizzled chunks
    const int tid = threadIdx.x;

    for (int idx = tid; idx < 1200; idx += 256) {
        int k = idx >> 2, sub = idx & 3;
        const u16* kp = qkv + ((size_t)(bi * 300 + k)) * 768 + 256 + h * 32 + sub * 8;
        *(uint4*)&Ks[k][sub * 8] = *(const uint4*)kp;
    }
    for (int idx = tid; idx < 600; idx += 256) {
        int kp2 = idx >> 2, sub = idx & 3;
        int k0 = kp2 * 2;
        const u16* vp = qkv + ((size_t)(bi * 300 + k0)) * 768 + 512 + h * 32 + sub * 8;
        uint4 v0 = *(const uint4*)vp;
        uint4 v1 = *(const uint4*)(vp + 768);
        u16 a0[8], a1[8];
        *(uint4*)a0 = v0; *(uint4*)a1 = v1;
#pragma unroll
        for (int j = 0; j < 8; ++j) {
            int d = sub * 8 + j;
            *(u32*)&Vt[d][VIDX(d, k0)] = (u32)a0[j] | ((u32)a1[j] << 16);
        }
    }
    for (int idx = tid; idx < 320; idx += 256) {
        int d = idx & 31, k0 = 300 + (idx >> 5) * 2;
        *(u32*)&Vt[d][VIDX(d, k0)] = 0;
    }
    __syncthreads();

    const int lane = tid & 63, wave = tid >> 6;
    const int c = lane & 15, g = lane >> 4;
    const int fk = g * 8;
    const f32x4 zero = { 0.f, 0.f, 0.f, 0.f };
    const float SCL2 = 0.25505416f;           // (1/sqrt(32)) * log2(e)
    const int sA = c + ((g & 1) << 5);
    const int sB = sA + 16;
    const bool hi = g >= 2;

    for (int qt = seg * 4 + wave; qt < 19; qt += 4 * S) {
        int qrow = qt * 16 + c; if (qrow > 299) qrow = 299;
        s16x8 afq = *(const s16x8*)(qkv + ((size_t)(bi * 300 + qrow)) * 768 + h * 32 + fk);
        f32x4 acc0 = zero, acc1 = zero;
        float m = -1e30f, l = 0.f;

        for (int kc = 0; kc < 5; ++kc) {
            const int kb = kc * 64;
            s16x8 ak0 = *(const s16x8*)&Ks[kb + c][fk];
            s16x8 ak1 = *(const s16x8*)&Ks[kb + 16 + c][fk];
            s16x8 ak2 = *(const s16x8*)&Ks[kb + 32 + c][fk];
            s16x8 ak3 = *(const s16x8*)&Ks[kb + 48 + c][fk];
            __builtin_amdgcn_s_setprio(1);
            f32x4 s0 = __builtin_amdgcn_mfma_f32_16x16x32_bf16(ak0, afq, zero, 0, 0, 0);
            f32x4 s1 = __builtin_amdgcn_mfma_f32_16x16x32_bf16(ak1, afq, zero, 0, 0, 0);
            f32x4 s2 = __builtin_amdgcn_mfma_f32_16x16x32_bf16(ak2, afq, zero, 0, 0, 0);
            f32x4 s3 = __builtin_amdgcn_mfma_f32_16x16x32_bf16(ak3, afq, zero, 0, 0, 0);
            __builtin_amdgcn_s_setprio(0);
            if (kb == 256) {   // keys >= 300 invalid (overwrite kills NaN)
#pragma unroll
                for (int j = 0; j < 4; ++j) {
                    if (g == 3) s2[j] = -1e30f;
                    s3[j] = -1e30f;
                }
            }
            float cm = fmaxf(fmaxf(fmaxf(s0[0], s0[1]), fmaxf(s0[2], s0[3])),
                             fmaxf(fmaxf(s1[0], s1[1]), fmaxf(s1[2], s1[3])));
            float cm2 = fmaxf(fmaxf(fmaxf(s2[0], s2[1]), fmaxf(s2[2], s2[3])),
                              fmaxf(fmaxf(s3[0], s3[1]), fmaxf(s3[2], s3[3])));
            cm = fmaxf(cm, cm2);
            cm = fmaxf(cm, __shfl_xor(cm, 16));
            cm = fmaxf(cm, __shfl_xor(cm, 32));
            float mn = fmaxf(m, cm);
            float corr = exp2f((m - mn) * SCL2);
            m = mn;
            float p0[4], p1[4], p2[4], p3[4];
#pragma unroll
            for (int j = 0; j < 4; ++j) {
                p0[j] = exp2f((s0[j] - m) * SCL2);
                p1[j] = exp2f((s1[j] - m) * SCL2);
                p2[j] = exp2f((s2[j] - m) * SCL2);
                p3[j] = exp2f((s3[j] - m) * SCL2);
            }
            float cs = ((p0[0] + p0[1]) + (p0[2] + p0[3]))
                     + ((p1[0] + p1[1]) + (p1[2] + p1[3]))
                     + ((p2[0] + p2[1]) + (p2[2] + p2[3]))
                     + ((p3[0] + p3[1]) + (p3[2] + p3[3]));
            cs += __shfl_xor(cs, 16);
            cs += __shfl_xor(cs, 32);
            l = l * corr + cs;
            u32 w0 = pkbf(p0[0], p0[1]), w1 = pkbf(p0[2], p0[3]);
            u32 w2 = pkbf(p1[0], p1[1]), w3 = pkbf(p1[2], p1[3]);
            u32 w4 = pkbf(p2[0], p2[1]), w5 = pkbf(p2[2], p2[3]);
            u32 w6 = pkbf(p3[0], p3[1]), w7 = pkbf(p3[2], p3[3]);
            int x0 = __shfl((int)w0, sA), x1 = __shfl((int)w1, sA);
            int x2 = __shfl((int)w2, sA), x3 = __shfl((int)w3, sA);
            int y0 = __shfl((int)w0, sB), y1 = __shfl((int)w1, sB);
            int y2 = __shfl((int)w2, sB), y3 = __shfl((int)w3, sB);
            union { u32 w[4]; s16x8 v; } afpA;
            afpA.w[0] = hi ? (u32)x2 : (u32)x0;
            afpA.w[1] = hi ? (u32)x3 : (u32)x1;
            afpA.w[2] = hi ? (u32)y2 : (u32)y0;
            afpA.w[3] = hi ? (u32)y3 : (u32)y1;
            int x4 = __shfl((int)w4, sA), x5 = __shfl((int)w5, sA);
            int x6 = __shfl((int)w6, sA), x7 = __shfl((int)w7, sA);
            int y4 = __shfl((int)w4, sB), y5 = __shfl((int)w5, sB);
            int y6 = __shfl((int)w6, sB), y7 = __shfl((int)w7, sB);
            union { u32 w[4]; s16x8 v; } afpB;
            afpB.w[0] = hi ? (u32)x6 : (u32)x4;
            afpB.w[1] = hi ? (u32)x7 : (u32)x5;
            afpB.w[2] = hi ? (u32)y6 : (u32)y4;
            afpB.w[3] = hi ? (u32)y7 : (u32)y5;
            float c0 = __shfl(corr, g * 4 + 0), c1 = __shfl(corr, g * 4 + 1);
            float c2 = __shfl(corr, g * 4 + 2), c3 = __shfl(corr, g * 4 + 3);
            acc0[0] *= c0; acc0[1] *= c1; acc0[2] *= c2; acc0[3] *= c3;
            acc1[0] *= c0; acc1[1] *= c1; acc1[2] *= c2; acc1[3] *= c3;
            s16x8 bv0 = *(const s16x8*)&Vt[c][VIDX(c, kb + fk)];
            s16x8 bv1 = *(const s16x8*)&Vt[16 + c][VIDX(16 + c, kb + fk)];
            s16x8 bv2 = *(const s16x8*)&Vt[c][VIDX(c, kb + 32 + fk)];
            s16x8 bv3 = *(const s16x8*)&Vt[16 + c][VIDX(16 + c, kb + 32 + fk)];
            __builtin_amdgcn_s_setprio(1);
            acc0 = __builtin_amdgcn_mfma_f32_16x16x32_bf16(afpA.v, bv0, acc0, 0, 0, 0);
            acc1 = __builtin_amdgcn_mfma_f32_16x16x32_bf16(afpA.v, bv1, acc1, 0, 0, 0);
            acc0 = __builtin_amdgcn_mfma_f32_16x16x32_bf16(afpB.v, bv2, acc0, 0, 0, 0);
            acc1 = __builtin_amdgcn_mfma_f32_16x16x32_bf16(afpB.v, bv3, acc1, 0, 0, 0);
            __builtin_amdgcn_s_setprio(0);
        }
        float l0 = __shfl(l, g * 4 + 0), l1 = __shfl(l, g * 4 + 1);
        float l2 = __shfl(l, g * 4 + 2), l3 = __shfl(l, g * 4 + 3);
        float lj[4] = { l0, l1, l2, l3 };
#pragma unroll
        for (int j = 0; j < 4; ++j) {
            int q = qt * 16 + g * 4 + j;
            if (q < 300) {
                float r = 1.f / lj[j];
                u16* op = O + ((size_t)(bi * 300 + q)) * 256 + h * 32;
                op[c]      = f2b(acc0[j] * r);
                op[16 + c] = f2b(acc1[j] * r);
            }
        }
    }
}

// sc_x[(b*16+nc)*300+nq][c] = sub_contour_query[b][nq][nc][c]  (bf16 out)
__global__ __launch_bounds__(256) void sc_transpose(
    const float* __restrict__ scq, u16* __restrict__ out)
{
    int row = blockIdx.x * 4 + (threadIdx.x >> 6);
    int c4 = (threadIdx.x & 63) * 4;
    int b = row / 4800;
    int rem = row % 4800;
    int nc = rem / 300, nq = rem % 300;
    float4 v = *(const float4*)(scq + ((size_t)((b * 300 + nq) * 16 + nc)) * 256 + c4);
    u16 u[4] = { f2b(v.x), f2b(v.y), f2b(v.z), f2b(v.w) };
    *(uint2*)(out + (size_t)row * 256 + c4) = *(const uint2*)u;
}

// tgt = LN( scq + 2*(sc_o + inst_o) ); 4 rows/block, row == wave, no LDS
__global__ __launch_bounds__(256) void ln1_combine(
    const float* __restrict__ scq, const float* __restrict__ sco,
    const float* __restrict__ insto, const float* __restrict__ g,
    const float* __restrict__ bta, float* __restrict__ tgt,
    u16* __restrict__ tgtb)
{
    int row = blockIdx.x * 4 + (threadIdx.x >> 6);
    int c4 = (threadIdx.x & 63) * 4;
    int b = row / 4800;
    int rem = row % 4800;
    int nq = rem >> 4, nc = rem & 15;
    float4 a = *(const float4*)(scq + (size_t)row * 256 + c4);
    float4 s = *(const float4*)(sco + ((size_t)((b * 16 + nc) * 300 + nq)) * 256 + c4);
    float4 i = *(const float4*)(insto + ((size_t)(b * 300 + nq)) * 256 + c4);
    float4 v = { a.x + 2.f * (s.x + i.x), a.y + 2.f * (s.y + i.y),
                 a.z + 2.f * (s.z + i.z), a.w + 2.f * (s.w + i.w) };
    float sm = v.x + v.y + v.z + v.w;
    float s2 = v.x * v.x + v.y * v.y + v.z * v.z + v.w * v.w;
#pragma unroll
    for (int o = 32; o; o >>= 1) { sm += __shfl_xor(sm, o); s2 += __shfl_xor(s2, o); }
    float mean = sm * (1.f / 256.f);
    float rstd = 1.f / sqrtf(s2 * (1.f / 256.f) - mean * mean + 1e-5f);
    float4 gv = *(const float4*)(g + c4);
    float4 bv = *(const float4*)(bta + c4);
    float4 r = { (v.x - mean) * rstd * gv.x + bv.x, (v.y - mean) * rstd * gv.y + bv.y,
                 (v.z - mean) * rstd * gv.z + bv.z, (v.w - mean) * rstd * gv.w + bv.w };
    *(float4*)(tgt + (size_t)row * 256 + c4) = r;
    u16 u[4] = { f2b(r.x), f2b(r.y), f2b(r.z), f2b(r.w) };
    *(uint2*)(tgtb + (size_t)row * 256 + c4) = *(const uint2*)u;
}

// dst = LN(x + y); optional bf16 copy; 4 rows/block, row == wave, no LDS
__global__ __launch_bounds__(256) void ln_add(
    const float* __restrict__ x, const float* __restrict__ y,
    const float* __restrict__ g, const float* __restrict__ bta,
    float* __restrict__ dst, u16* __restrict__ bdst)
{
    int row = blockIdx.x * 4 + (threadIdx.x >> 6);
    int c4 = (threadIdx.x & 63) * 4;
    float4 a = *(const float4*)(x + (size_t)row * 256 + c4);
    float4 b = *(const float4*)(y + (size_t)row * 256 + c4);
    float4 v = { a.x + b.x, a.y + b.y, a.z + b.z, a.w + b.w };
    float sm = v.x + v.y + v.z + v.w;
    float s2 = v.x * v.x + v.y * v.y + v.z * v.z + v.w * v.w;
#pragma unroll
    for (int o = 32; o; o >>= 1) { sm += __shfl_xor(sm, o); s2 += __shfl_xor(s2, o); }
    float mean = sm * (1.f / 256.f);
    float rstd = 1.f / sqrtf(s2 * (1.f / 256.f) - mean * mean + 1e-5f);
    float4 gv = *(const float4*)(g + c4);
    float4 bv = *(const float4*)(bta + c4);
    float4 r = { (v.x - mean) * rstd * gv.x + bv.x, (v.y - mean) * rstd * gv.y + bv.y,
                 (v.z - mean) * rstd * gv.z + bv.z, (v.w - mean) * rstd * gv.w + bv.w };
    *(float4*)(dst + (size_t)row * 256 + c4) = r;
    if (bdst) {
        u16 u[4] = { f2b(r.x), f2b(r.y), f2b(r.z), f2b(r.w) };
        *(uint2*)(bdst + (size_t)row * 256 + c4) = *(const uint2*)u;
    }
}

// ---------------------------------------------------------------------------
// deformable bilinear sampling + aw-softmax reduce over NP=4 (bf16 out).
// ---------------------------------------------------------------------------
__global__ __launch_bounds__(256) void deform_sample(
    const float* __restrict__ oaw, const float* __restrict__ refb,
    const float* __restrict__ mem, u16* __restrict__ samp)
{
    const int row = blockIdx.x;
    const int b = row / 4800;
    const int tid = threadIdx.x;
    const int h = tid >> 5;
    const float4 rb = *(const float4*)(refb + (size_t)row * 4);
    const float* base = oaw + (size_t)row * 128;
    float a0 = base[64 + h * 4 + 0], a1 = base[64 + h * 4 + 1];
    float a2 = base[64 + h * 4 + 2], a3 = base[64 + h * 4 + 3];
    float am = fmaxf(fmaxf(a0, a1), fmaxf(a2, a3));
    float e0 = __expf(a0 - am), e1 = __expf(a1 - am), e2 = __expf(a2 - am), e3 = __expf(a3 - am);
    float rs = 1.f / (e0 + e1 + e2 + e3);
    float wp[4] = { e0 * rs, e1 * rs, e2 * rs, e3 * rs };
    const float* op = base + h * 8;
    const float* mb = mem + (size_t)b * 16384 * 256 + tid;

    int offs[16];
    float wts[16];
#pragma unroll
    for (int p = 0; p < 4; ++p) {
        float gx = (rb.x + op[p * 2 + 0] * rb.z * 0.5f) * 128.f - 0.5f;
        float gy = (rb.y + op[p * 2 + 1] * rb.w * 0.5f) * 128.f - 0.5f;
        float x0f = floorf(gx), y0f = floorf(gy);
        int x0 = (int)x0f, y0 = (int)y0f;
        float wx1 = gx - x0f, wy1 = gy - y0f;
        float wx0 = 1.f - wx1, wy0 = 1.f - wy1;
        float vx0 = ((unsigned)x0 < 128u) ? 1.f : 0.f;
        float vx1 = ((unsigned)(x0 + 1) < 128u) ? 1.f : 0.f;
        float vy0 = ((unsigned)y0 < 128u) ? 1.f : 0.f;
        float vy1 = ((unsigned)(y0 + 1) < 128u) ? 1.f : 0.f;
        int xc0 = min(max(x0, 0), 127), xc1 = min(max(x0 + 1, 0), 127);
        int yc0 = min(max(y0, 0), 127), yc1 = min(max(y0 + 1, 0), 127);
        offs[p * 4 + 0] = (yc0 * 128 + xc0) << 8;
        offs[p * 4 + 1] = (yc0 * 128 + xc1) << 8;
        offs[p * 4 + 2] = (yc1 * 128 + xc0) << 8;
        offs[p * 4 + 3] = (yc1 * 128 + xc1) << 8;
        wts[p * 4 + 0] = wp[p] * wx0 * wy0 * vx0 * vy0;
        wts[p * 4 + 1] = wp[p] * wx1 * wy0 * vx1 * vy0;
        wts[p * 4 + 2] = wp[p] * wx0 * wy1 * vx0 * vy1;
        wts[p * 4 + 3] = wp[p] * wx1 * wy1 * vx1 * vy1;
    }
    float vals[16];
#pragma unroll
    for (int i = 0; i < 16; ++i) vals[i] = mb[offs[i]];
    float acc = 0.f;
#pragma unroll
    for (int i = 0; i < 16; ++i) acc = fmaf(vals[i], wts[i], acc);
    samp[(size_t)row * 256 + tid] = f2b(acc);
}

extern "C" void kernel_launch(void* const* d_in, const int* in_sizes, int n_in,
                              void* d_out, int out_size, void* d_ws, size_t ws_size,
                              hipStream_t stream) {
    const float* inst_query = (const float*)d_in[0];
    const float* sub_contour = (const float*)d_in[1];
    const float* memory_feats = (const float*)d_in[2];
    const float* ref_boxes = (const float*)d_in[3];
    const float* inst_in_w = (const float*)d_in[4];
    const float* inst_in_b = (const float*)d_in[5];
    const float* inst_out_w = (const float*)d_in[6];
    const float* inst_out_b = (const float*)d_in[7];
    const float* sc_in_w = (const float*)d_in[8];
    const float* sc_in_b = (const float*)d_in[9];
    const float* sc_out_w = (const float*)d_in[10];
    const float* sc_out_b = (const float*)d_in[11];
    const float* off_w = (const float*)d_in[12];
    const float* off_b = (const float*)d_in[13];
    const float* aw_w = (const float*)d_in[14];
    const float* aw_b = (const float*)d_in[15];
    const float* outp_w = (const float*)d_in[16];
    const float* outp_b = (const float*)d_in[17];
    const float* lin1_w = (const float*)d_in[18];
    const float* lin1_b = (const float*)d_in[19];
    const float* lin2_w = (const float*)d_in[20];
    const float* lin2_b = (const float*)d_in[21];
    const float* n1_g = (const float*)d_in[22];
    const float* n1_b = (const float*)d_in[23];
    const float* n2_g = (const float*)d_in[24];
    const float* n2_b = (const float*)d_in[25];
    const float* n3_g = (const float*)d_in[26];
    const float* n3_b = (const float*)d_in[27];

    // ---- workspace layout ----
    u16* wsb = (u16*)d_ws;
    u16* qkv_b   = wsb;                       // 19200*768  = 14,745,600
    u16* xbuf_b  = qkv_b + 14745600;          //  4,915,200
    u16* obuf_b  = xbuf_b + 4915200;          //  4,915,200
    u16* tgt_b   = obuf_b + 4915200;          //  4,915,200
    u16* w_inst_in  = tgt_b + 4915200;        //    196,608
    u16* w_inst_out = w_inst_in + 196608;     //     65,536
    u16* w_sc_in    = w_inst_out + 65536;     //    196,608
    u16* w_sc_out   = w_sc_in + 196608;       //     65,536
    u16* w_outp     = w_sc_out + 65536;       //     65,536
    u16* w_lin1     = w_outp + 65536;         //    524,288
    u16* w_lin2     = w_lin1 + 524288;        //    524,288
    u16* w_offaw    = w_lin2 + 524288;        //     32,768
    u16* ffn1_b = qkv_b;                      // alias (2-chunk fallback)
    u16* instq_b = tgt_b;                     // temp (tgt_b not live yet)
    float* fp    = (float*)(w_offaw + 32768);
    float* insto = fp;                        //    307,200
    float* tgt   = insto + 307200;            //  4,915,200
    float* t2    = tgt + 4915200;             //  4,915,200
    float* oawb  = t2 + 4915200;              //  2,457,600
    float* b_offaw = oawb + 2457600;          //        128
    // full-FFN scratch (if workspace allows): 19200*2048 bf16 after base
    size_t base_bytes = (size_t)((char*)(b_offaw + 128) - (char*)d_ws);
    size_t ffn_off = (base_bytes + 255) & ~(size_t)255;
    u16* ffn1_full = (u16*)((char*)d_ws + ffn_off);
    bool full_ffn = ws_size >= ffn_off + (size_t)2 * 19200 * 2048;

    dim3 blk(256);

    // fused weight/activation conversions
    Cvt8 ca;
    ca.s[0] = { inst_in_w,  w_inst_in,  196608 / 8 };
    ca.s[1] = { inst_out_w, w_inst_out, 65536 / 8 };
    ca.s[2] = { sc_in_w,    w_sc_in,    196608 / 8 };
    ca.s[3] = { sc_out_w,   w_sc_out,   65536 / 8 };
    ca.s[4] = { outp_w,     w_outp,     65536 / 8 };
    ca.s[5] = { lin1_w,     w_lin1,     524288 / 8 };
    ca.s[6] = { lin2_w,     w_lin2,     524288 / 8 };
    ca.s[7] = { inst_query, instq_b,    307200 / 8 };
    int totalv = (196608 * 2 + 65536 * 3 + 524288 * 2 + 307200) / 8;
    cvt_multi<<<(totalv + 255) / 256, blk, 0, stream>>>(ca, totalv);
    pack_offaw<<<128, blk, 0, stream>>>(off_w, off_b, aw_w, aw_b, w_offaw, b_offaw);

    // 1. inst QKV -> qkv_b (bf16)   [K=256: BK=128]
    gemm_mfma<0,1,128,128><<<dim3(6, 10), blk, 0, stream>>>(instq_b, w_inst_in, inst_in_b, qkv_b, 1200, 768, 256, 256);
    // 2. inst attention (NBH=32, S=4)
    attn_mfma<<<128, blk, 0, stream>>>(qkv_b, obuf_b, 4, 32);
    // 3. inst out-proj -> insto (fp32)
    gemm_mfma<0,0,64,128><<<dim3(2, 19), blk, 0, stream>>>(obuf_b, w_inst_out, inst_out_b, insto, 1200, 256, 256, 256);
    // 4. sc transpose -> xbuf_b (bf16)
    sc_transpose<<<4800, blk, 0, stream>>>(sub_contour, xbuf_b);
    // 5. sc QKV
    gemm_mfma<0,1,128,128><<<dim3(6, 150), blk, 0, stream>>>(xbuf_b, w_sc_in, sc_in_b, qkv_b, 19200, 768, 256, 256);
    // 6. sc attention (S=2, NBH=512 seg-major)
    attn_mfma<<<1024, blk, 0, stream>>>(qkv_b, obuf_b, 2, 512);
    // 7. sc out-proj -> t2 (fp32, sc row order)
    gemm_mfma<0,0,64,128><<<dim3(2, 300), blk, 0, stream>>>(obuf_b, w_sc_out, sc_out_b, t2, 19200, 256, 256, 256);
    // 8. combine + LN1 -> tgt (fp32) + tgt_b (bf16)
    ln1_combine<<<4800, blk, 0, stream>>>(sub_contour, t2, insto, n1_g, n1_b, tgt, tgt_b);
    // 9. packed off+aw projection -> oawb [19200][128]
    gemm_mfma<0,0,64,128><<<dim3(1, 300), blk, 0, stream>>>(tgt_b, w_offaw, b_offaw, oawb, 19200, 128, 256, 256);
    // 10. deformable sampling -> obuf_b (bf16)
    deform_sample<<<19200, blk, 0, stream>>>(oawb, ref_boxes, memory_feats, obuf_b);
    // 11. outp proj -> t2
    gemm_mfma<0,0,64,128><<<dim3(2, 300), blk, 0, stream>>>(obuf_b, w_outp, outp_b, t2, 19200, 256, 256, 256);
    // 12. LN2 -> tgt (fp32) + tgt_b (bf16)
    ln_add<<<4800, blk, 0, stream>>>(tgt, t2, n2_g, n2_b, tgt, tgt_b);
    // 13. FFN: lin1 TM=64/BK=128; lin2 TM=64/BK=128 (16 K-steps instead of 32;
    //     49KB LDS caps 3 blocks/CU but grid supplies only 2.34 — free win).
    if (full_ffn) {
        gemm_mfma<1,1,64,128><<<dim3(16, 300), blk, 0, stream>>>(tgt_b, w_lin1, lin1_b, ffn1_full, 19200, 2048, 256, 256);
        gemm_mfma<0,0,64,128><<<dim3(2, 300), blk, 0, stream>>>(ffn1_full, w_lin2, lin2_b, t2, 19200, 256, 2048, 2048);
    } else {
        for (int c = 0; c < 2; ++c) {
            gemm_mfma<1,1,64,128><<<dim3(16, 150), blk, 0, stream>>>(tgt_b + (size_t)c * 9600 * 256, w_lin1, lin1_b, ffn1_b, 9600, 2048, 256, 256);
            gemm_mfma<0,0,64,128><<<dim3(2, 150), blk, 0, stream>>>(ffn1_b, w_lin2, lin2_b, t2 + (size_t)c * 9600 * 256, 9600, 256, 2048, 2048);
        }
    }
    // 14. LN3 -> output fp32 (B, NQ, NC, C)
    ln_add<<<4800, blk, 0, stream>>>(tgt, t2, n3_g, n3_b, (float*)d_out, nullptr);
}